// Round 8
// baseline (462.848 us; speedup 1.0000x reference)
//
#include <hip/hip_runtime.h>
#include <hip/hip_bf16.h>
#include <math.h>

#define HW   36864        // 192*192
#define BHW  73728        // 2*HW

typedef float f32x4 __attribute__((ext_vector_type(4)));
typedef short short8 __attribute__((ext_vector_type(8)));
typedef short s16x4 __attribute__((ext_vector_type(4)));   // NB: 'short4' is a HIP built-in type

__device__ __forceinline__ unsigned f2bf(float f) {        // fp32 -> bf16 bits, RNE
    unsigned u = __float_as_uint(f);
    return (u + 0x7fffu + ((u >> 16) & 1u)) >> 16;
}
__device__ __forceinline__ float bf2f(unsigned short s) {  // bf16 bits -> fp32
    return __uint_as_float(((unsigned)s) << 16);
}
__device__ __forceinline__ float gelu_erf(float v) {
    return v * 0.5f * (1.0f + erff(v * 0.70710678118654752f));
}

// ---------------------------------------------------------------- weight prep
// fc1 weights/bias PAIRED: col 2c = u-channel c, col 2c+1 = v-channel c (fused gate epilogue).
__global__ __launch_bounds__(256)
void wconv_kernel(const float* __restrict__ w1, const float* __restrict__ w2,
                  const float* __restrict__ wq, const float* __restrict__ wp,
                  const float* __restrict__ wf1, const float* __restrict__ wf2,
                  const float* __restrict__ dww, const float* __restrict__ fb1,
                  ushort* __restrict__ o1, ushort* __restrict__ o2, ushort* __restrict__ oq,
                  ushort* __restrict__ op, ushort* __restrict__ of1, ushort* __restrict__ of2,
                  float* __restrict__ dwt, float* __restrict__ bg)
{
    int i = blockIdx.x * 256 + threadIdx.x;
    if      (i <  65536) o1 [i         ] = (ushort)f2bf(w1 [i         ]);
    else if (i <  98304) o2 [i -  65536] = (ushort)f2bf(w2 [i -  65536]);
    else if (i < 147456) oq [i -  98304] = (ushort)f2bf(wq [i -  98304]);
    else if (i < 163840) op [i - 147456] = (ushort)f2bf(wp [i - 147456]);
    else if (i < 229376) {
        int j = i - 163840;            // paired fc1: col=j>>7, k=j&127
        int col = j >> 7, k = j & 127;
        of1[j] = (ushort)f2bf(wf1[((size_t)((col & 1) * 256 + (col >> 1))) * 128 + k]);
    }
    else if (i < 262144) of2[i - 229376] = (ushort)f2bf(wf2[i - 229376]);
    else if (i < 266752) {
        int j = i - 262144;            // j = tap*512 + c
        int tap = j >> 9, c = j & 511;
        dwt[j] = dww[c * 9 + tap];
    }
    else if (i < 267264) {
        int j = i - 266752;            // paired fc1 bias
        bg[j] = fb1[(j & 1) * 256 + (j >> 1)];
    }
}

// ---------------------------------------------------------------- rmsnorm (NCHW fp32 -> pixel-major bf16)
__global__ __launch_bounds__(256)
void rmsnorm_t_kernel(const float* __restrict__ src, const float* __restrict__ s,
                      const float* __restrict__ bi, __hip_bfloat16* __restrict__ dst)
{
    int P = blockIdx.x * 256 + threadIdx.x;          // pixel id in [0, BHW)
    int b = P / HW, pp = P - b * HW;
    const float* xb = src + (size_t)b * 128 * HW + pp;
    float ss = 0.f;
#pragma unroll 8
    for (int c = 0; c < 128; ++c) { float v = xb[(size_t)c * HW]; ss = fmaf(v, v, ss); }
    float inv = 1.0f / sqrtf(ss * 0.0078125f + 1e-6f);
    unsigned* drow = (unsigned*)(dst + (size_t)P * 128);
#pragma unroll 4
    for (int c = 0; c < 128; c += 2) {
        float v0 = fmaf(s[c]     * xb[(size_t)c * HW],       inv, bi[c]);
        float v1 = fmaf(s[c + 1] * xb[(size_t)(c + 1) * HW], inv, bi[c + 1]);
        drow[c >> 1] = f2bf(v0) | (f2bf(v1) << 16);
    }
}

// ---------------------------------------------------------------- MFMA GEMM
// MODE 0: store bf16 pixel-major (BHW,N) via LDS-transposed 16B stores.
// MODE 1: N==128; rdst(NCHW fp32) = rsrc + scale*C (LDS-transposed coalesced stores).
// MODE 2: N==512 paired u/v cols; store u*gelu(v) bf16 (BHW,256), LDS-transposed.
// MODE 3: MODE 1 + fused RMSNorm: also emits xn bf16 pixel-major (BHW,128).
template<int K, int MODE>
__global__ __launch_bounds__(256)
void gemm_kernel(const __hip_bfloat16* __restrict__ Abf, const __hip_bfloat16* __restrict__ Wbf,
                 const float* __restrict__ bias, int N,
                 __hip_bfloat16* __restrict__ outb,
                 const float* __restrict__ rsrc, float* __restrict__ rdst,
                 const float* __restrict__ scale,
                 const float* __restrict__ rms_s, const float* __restrict__ rms_b,
                 __hip_bfloat16* __restrict__ xn)
{
    constexpr int SMEM = (MODE == 3) ? 56320 : ((MODE == 1) ? 34816 :
                         ((MODE == 0) ? 17408 : 16384));
    __shared__ char smem[SMEM];
    short* sA = (short*)smem;
    short* sB = sA + 4096;
    float* sEp = (float*)smem;                       // MODE1/3: [128 ch][68 px]
    float* sPar = (float*)(smem + 34816);            // MODE3: [64 px][17]
    float* sInv = (float*)(smem + 39168);            // MODE3: [64 px]
    ushort* sXn = (ushort*)(smem + 39424);           // MODE3: [64 px][132 ch-pad]

    const short* A = (const short*)Abf;
    const short* W = (const short*)Wbf;

    int t = threadIdx.x;
    int lane = t & 63, wv = t >> 6;
    int wm = wv & 1, wn = wv >> 1;
    int m0 = blockIdx.x * 128;
    int n0 = blockIdx.y * 128;
    int q = lane >> 4, r16 = lane & 15;

    f32x4 acc[4][4];
#pragma unroll
    for (int nt = 0; nt < 4; ++nt) {
        float bv = bias[n0 + wn * 64 + nt * 16 + r16];
#pragma unroll
        for (int mt = 0; mt < 4; ++mt) acc[mt][nt] = (f32x4){bv, bv, bv, bv};
    }

    for (int kk = 0; kk < K; kk += 32) {
#pragma unroll
        for (int i = 0; i < 2; ++i) {
            int rbase = wv * 32 + i * 16;
            int row = rbase + (lane >> 2);
            int kc = (lane & 3) ^ ((row >> 1) & 3);
            const short* ga = A + (size_t)(m0 + row) * K + kk + kc * 8;
            const short* gb = W + (size_t)(n0 + row) * K + kk + kc * 8;
            __builtin_amdgcn_global_load_lds((const __attribute__((address_space(1))) void*)ga,
                                             (__attribute__((address_space(3))) void*)(sA + rbase * 32), 16, 0, 0);
            __builtin_amdgcn_global_load_lds((const __attribute__((address_space(1))) void*)gb,
                                             (__attribute__((address_space(3))) void*)(sB + rbase * 32), 16, 0, 0);
        }
        __syncthreads();

        short8 af[4], bf[4];
#pragma unroll
        for (int mt = 0; mt < 4; ++mt) {
            int r = wm * 64 + mt * 16 + r16;
            af[mt] = *(const short8*)(sA + (r * 4 + (q ^ ((r >> 1) & 3))) * 8);
        }
#pragma unroll
        for (int nt = 0; nt < 4; ++nt) {
            int r = wn * 64 + nt * 16 + r16;
            bf[nt] = *(const short8*)(sB + (r * 4 + (q ^ ((r >> 1) & 3))) * 8);
        }
#pragma unroll
        for (int mt = 0; mt < 4; ++mt)
#pragma unroll
            for (int nt = 0; nt < 4; ++nt)
                acc[mt][nt] = __builtin_amdgcn_mfma_f32_16x16x32_bf16(af[mt], bf[nt], acc[mt][nt], 0, 0, 0);
        __syncthreads();
    }

    if constexpr (MODE == 0) {
        // LDS-transposed bf16 epilogue: sC [64 rows][136 cols-pad], 16B coalesced stores.
        ushort* sC = (ushort*)smem;
        ushort* ob = (ushort*)outb;
        for (int h = 0; h < 2; ++h) {
            __syncthreads();           // staging-reuse / WAR fence
            if (wm == h) {
#pragma unroll
                for (int mt = 0; mt < 4; ++mt)
#pragma unroll
                    for (int nt = 0; nt < 4; ++nt) {
                        int row = mt * 16 + q * 4;
                        int col = wn * 64 + nt * 16 + r16;
#pragma unroll
                        for (int rg = 0; rg < 4; ++rg)
                            sC[(row + rg) * 136 + col] = (ushort)f2bf(acc[mt][nt][rg]);
                    }
            }
            __syncthreads();
            int px = t >> 2, ck = t & 3;
            size_t base = (size_t)(m0 + h * 64 + px) * N + n0;
#pragma unroll
            for (int g = 0; g < 4; ++g) {
                int co = (ck * 4 + g) * 8;
                *(short8*)(ob + base + co) = *(const short8*)(sC + px * 136 + co);
            }
        }
    } else if constexpr (MODE == 2) {
        // fused FFN gate + LDS-transposed bf16 epilogue: sG [64 rows][72 gch-pad]
        ushort* sG = (ushort*)smem;
        ushort* ob = (ushort*)outb;
        int parity = r16 & 1;
        for (int h = 0; h < 2; ++h) {
            __syncthreads();
            if (wm == h) {
#pragma unroll
                for (int mt = 0; mt < 4; ++mt)
#pragma unroll
                    for (int nt = 0; nt < 4; ++nt) {
                        int row = mt * 16 + q * 4;
                        int gch = (wn * 64 + nt * 16 + r16) >> 1;
#pragma unroll
                        for (int rg = 0; rg < 4; ++rg) {
                            float val = acc[mt][nt][rg];
                            float part = __shfl_xor(val, 1);
                            float uu = parity ? part : val;
                            float vv = parity ? val : part;
                            float g = uu * gelu_erf(vv);
                            if (!parity) sG[(row + rg) * 72 + gch] = (ushort)f2bf(g);
                        }
                    }
            }
            __syncthreads();
            int px = t >> 2, ck = t & 3;
            size_t base = (size_t)(m0 + h * 64 + px) * 256 + (n0 >> 1);
#pragma unroll
            for (int g = 0; g < 2; ++g) {
                int co = (ck * 2 + g) * 8;
                *(short8*)(ob + base + co) = *(const short8*)(sG + px * 72 + co);
            }
        }
    } else {   // MODE 1 / 3
        float sc = scale[0];
        for (int h = 0; h < 2; ++h) {
            __syncthreads();
            if (wm == h) {
#pragma unroll
                for (int mt = 0; mt < 4; ++mt)
#pragma unroll
                    for (int nt = 0; nt < 4; ++nt) {
                        int c = wn * 64 + nt * 16 + r16;
                        int px = mt * 16 + q * 4;
#pragma unroll
                        for (int rg = 0; rg < 4; ++rg)
                            sEp[c * 68 + px + rg] = acc[mt][nt][rg];
                    }
            }
            __syncthreads();
            int c16 = t >> 4, l16 = t & 15;
            int p0 = m0 + h * 64 + l16 * 4;
            int b = p0 / HW, pp = p0 - b * HW;
            f32x4 ov[8];
            f32x4 ps = (f32x4){0.f, 0.f, 0.f, 0.f};
#pragma unroll
            for (int i = 0; i < 8; ++i) {
                int c = c16 + i * 16;
                f32x4 v = *(const f32x4*)&sEp[c * 68 + l16 * 4];
                size_t gi = (size_t)(b * 128 + c) * HW + pp;
                f32x4 r = *(const f32x4*)&rsrc[gi];
                f32x4 o = r + sc * v;
                *(f32x4*)&rdst[gi] = o;
                if constexpr (MODE == 3) {
                    ov[i] = o;
#pragma unroll
                    for (int rg = 0; rg < 4; ++rg) ps[rg] = fmaf(o[rg], o[rg], ps[rg]);
                }
            }
            if constexpr (MODE == 3) {
#pragma unroll
                for (int rg = 0; rg < 4; ++rg) sPar[(l16 * 4 + rg) * 17 + c16] = ps[rg];
                __syncthreads();
                if (t < 64) {
                    float ssum = 0.f;
#pragma unroll
                    for (int j = 0; j < 16; ++j) ssum += sPar[t * 17 + j];
                    sInv[t] = 1.0f / sqrtf(ssum * 0.0078125f + 1e-6f);
                }
                __syncthreads();
                float iv[4];
#pragma unroll
                for (int rg = 0; rg < 4; ++rg) iv[rg] = sInv[l16 * 4 + rg];
#pragma unroll
                for (int i = 0; i < 8; ++i) {
                    int c = c16 + i * 16;
                    float scs = rms_s[c], bcs = rms_b[c];
#pragma unroll
                    for (int rg = 0; rg < 4; ++rg)
                        sXn[(l16 * 4 + rg) * 132 + c] = (ushort)f2bf(fmaf(scs * ov[i][rg], iv[rg], bcs));
                }
                __syncthreads();
                {
                    int px = t >> 2, qd = t & 3;
                    const ushort* src = sXn + px * 132 + qd * 32;
                    ushort* dst = (ushort*)xn + (size_t)(m0 + h * 64 + px) * 128 + qd * 32;
#pragma unroll
                    for (int g = 0; g < 4; ++g)
                        *(short8*)(dst + g * 8) = *(const short8*)(src + g * 8);
                }
            }
        }
    }
}

// ---------------------------------------------------------------- dwconv3x3 + gate, c4 x V4, hoisted weights
// 4 channels/thread, 4 vertical pixels/thread. Weights (9 taps x 4ch x u,v = 72 fp32)
// loaded ONCE into VGPRs; all 36 value loads branchless (clamp+mask) for max MLP.
__global__ __launch_bounds__(256, 3)
void dwgate_kernel(const __hip_bfloat16* __restrict__ t1, const float* __restrict__ dwt,
                   const float* __restrict__ dwb, __hip_bfloat16* __restrict__ tg)
{
    int t = threadIdx.x;
    int tc = t & 15;                   // 4-ch subchunk within 64-ch group
    int tp = t >> 4;                   // 0..15 pixel column
    int bx = blockIdx.x;
    int wseg = bx % 12; int tmp = bx / 12;
    int hq = tmp % 48; int b = tmp / 48;
    int cu = blockIdx.y * 64 + tc * 4; // u-channel base (0..252)
    int h0 = hq * 4;
    int w = wseg * 16 + tp;
    const ushort* t1u = (const ushort*)t1;

    f32x4 wu[9], wv[9];
#pragma unroll
    for (int tap = 0; tap < 9; ++tap) {
        wu[tap] = *(const f32x4*)(dwt + tap * 512 + cu);
        wv[tap] = *(const f32x4*)(dwt + tap * 512 + 256 + cu);
    }
    f32x4 bu = *(const f32x4*)(dwb + cu);
    f32x4 bv = *(const f32x4*)(dwb + 256 + cu);

    f32x4 au[4], av[4];
#pragma unroll
    for (int py = 0; py < 4; ++py) { au[py] = bu; av[py] = bv; }

#pragma unroll
    for (int r = 0; r < 6; ++r) {                    // source row h0-1+r
        int hh = h0 - 1 + r;
        bool okr = (unsigned)hh < 192u;
        int hhc = okr ? hh : 0;
#pragma unroll
        for (int dxi = 0; dxi < 3; ++dxi) {
            int w2 = w + dxi - 1;
            bool ok = okr && ((unsigned)w2 < 192u);
            int w2c = (w2 < 0) ? 0 : ((w2 > 191) ? 191 : w2);
            const ushort* p = t1u + (size_t)(b * HW + hhc * 192 + w2c) * 512 + cu;
            s16x4 u4 = *(const s16x4*)p;
            s16x4 v4 = *(const s16x4*)(p + 256);
            f32x4 uf, vf;
#pragma unroll
            for (int e = 0; e < 4; ++e) {
                uf[e] = ok ? bf2f((ushort)u4[e]) : 0.f;
                vf[e] = ok ? bf2f((ushort)v4[e]) : 0.f;
            }
#pragma unroll
            for (int py = 0; py < 4; ++py) {
                int dy = r - 1 - py;
                if (dy < -1 || dy > 1) continue;     // compile-time after unroll
                int tap = (dy + 1) * 3 + dxi;
#pragma unroll
                for (int e = 0; e < 4; ++e) {
                    au[py][e] = fmaf(wu[tap][e], uf[e], au[py][e]);
                    av[py][e] = fmaf(wv[tap][e], vf[e], av[py][e]);
                }
            }
        }
    }
#pragma unroll
    for (int py = 0; py < 4; ++py) {
        s16x4 o4;
#pragma unroll
        for (int e = 0; e < 4; ++e) o4[e] = (short)(ushort)f2bf(au[py][e] * gelu_erf(av[py][e]));
        int gp = b * HW + (h0 + py) * 192 + w;
        *(s16x4*)((ushort*)tg + (size_t)gp * 256 + cu) = o4;
    }
}

// ---------------------------------------------------------------- windowed attention (MFMA)
__device__ __forceinline__ int wpix(int wh, int ww, int m) {
    int ty = m >> 3, tx = m & 7;
    int hs = wh * 8 + ty + 4; if (hs >= 192) hs -= 192;
    int wsc = ww * 8 + tx + 4; if (wsc >= 192) wsc -= 192;
    return hs * 192 + wsc;
}
__device__ __forceinline__ int wreg(int wh, int ww, int m) {   // shift-mask region id
    int hr = wh * 8 + (m >> 3), wr = ww * 8 + (m & 7);
    return ((hr < 184) ? 0 : (hr < 188) ? 1 : 2) * 3 +
           ((wr < 184) ? 0 : (wr < 188) ? 1 : 2);
}

__global__ __launch_bounds__(256)
void attn_kernel(const __hip_bfloat16* __restrict__ qkv, const float* __restrict__ rpe,
                 __hip_bfloat16* __restrict__ attnout)
{
    __shared__ char smem[54288];
    int t = threadIdx.x;
    int lane = t & 63, head = t >> 6;
    int wh = blockIdx.x / 24, ww = blockIdx.x % 24;
    int b = blockIdx.y;
    int q = lane >> 4, r16 = lane & 15;

    float* rpe_s = (float*)(smem + 50688);
    for (int i = t; i < 900; i += 256) rpe_s[i] = rpe[i];

    char* Pbuf  = smem + head * 12672;
    char* VTbuf = Pbuf + 8448;
    const ushort* qkvu = (const ushort*)qkv;

    short8 aq[4], bk[4];
#pragma unroll
    for (int mt = 0; mt < 4; ++mt) {
        int pix = wpix(wh, ww, mt * 16 + r16);
        const ushort* rowp = qkvu + (size_t)(b * HW + pix) * 384 + head * 32 + q * 8;
        aq[mt] = *(const short8*)rowp;
        bk[mt] = *(const short8*)(rowp + 128);
    }
    {
        int pix = wpix(wh, ww, lane);
        const ushort* vp = qkvu + (size_t)(b * HW + pix) * 384 + 256 + head * 32;
        ushort* vt = (ushort*)VTbuf;           // VT[d][j]: row stride 66 ushorts
#pragma unroll
        for (int g = 0; g < 4; ++g) {
            short8 v8 = *(const short8*)(vp + g * 8);
#pragma unroll
            for (int e = 0; e < 8; ++e) vt[(g * 8 + e) * 66 + lane] = (ushort)v8[e];
        }
    }
    __syncthreads();

    f32x4 s[4][4];
#pragma unroll
    for (int mt = 0; mt < 4; ++mt)
#pragma unroll
        for (int nt = 0; nt < 4; ++nt) s[mt][nt] = (f32x4){0.f, 0.f, 0.f, 0.f};
#pragma unroll
    for (int mt = 0; mt < 4; ++mt)
#pragma unroll
        for (int nt = 0; nt < 4; ++nt)
            s[mt][nt] = __builtin_amdgcn_mfma_f32_16x16x32_bf16(aq[mt], bk[nt], s[mt][nt], 0, 0, 0);

    bool edge = (wh == 23) || (ww == 23);
    int tyj[4], txj[4], rgj[4];
#pragma unroll
    for (int nt = 0; nt < 4; ++nt) {
        int j = nt * 16 + r16;
        tyj[nt] = j >> 3; txj[nt] = j & 7;
        rgj[nt] = wreg(wh, ww, j);
    }
    float rinv[4][4];
#pragma unroll
    for (int mt = 0; mt < 4; ++mt) {
#pragma unroll
        for (int rg = 0; rg < 4; ++rg) {
            int i = mt * 16 + q * 4 + rg;
            int tyi = i >> 3, txi = i & 7;
            int rgi = edge ? wreg(wh, ww, i) : 0;
            float mx = -INFINITY;
#pragma unroll
            for (int nt = 0; nt < 4; ++nt) {
                float v = s[mt][nt][rg] * 0.17677669529663689f
                        + rpe_s[((tyi - tyj[nt] + 7) * 15 + (txi - txj[nt] + 7)) * 4 + head];
                if (edge && rgi != rgj[nt]) v = -INFINITY;
                s[mt][nt][rg] = v;
                mx = fmaxf(mx, v);
            }
            mx = fmaxf(mx, __shfl_xor(mx, 1));
            mx = fmaxf(mx, __shfl_xor(mx, 2));
            mx = fmaxf(mx, __shfl_xor(mx, 4));
            mx = fmaxf(mx, __shfl_xor(mx, 8));
            float sum = 0.f;
#pragma unroll
            for (int nt = 0; nt < 4; ++nt) {
                float e = __expf(s[mt][nt][rg] - mx);
                s[mt][nt][rg] = e;
                sum += e;
            }
            sum += __shfl_xor(sum, 1);
            sum += __shfl_xor(sum, 2);
            sum += __shfl_xor(sum, 4);
            sum += __shfl_xor(sum, 8);
            rinv[mt][rg] = 1.0f / sum;
        }
    }

    ushort* Pu = (ushort*)Pbuf;                 // row stride 66 ushorts
#pragma unroll
    for (int mt = 0; mt < 4; ++mt)
#pragma unroll
        for (int rg = 0; rg < 4; ++rg) {
            int i = mt * 16 + q * 4 + rg;
#pragma unroll
            for (int nt = 0; nt < 4; ++nt)
                Pu[i * 66 + nt * 16 + r16] = (ushort)f2bf(s[mt][nt][rg]);
        }
    __syncthreads();   // fence: P ushort-writes before uint-reads (TBAA)

    f32x4 o[4][2];
#pragma unroll
    for (int mt = 0; mt < 4; ++mt) { o[mt][0] = (f32x4){0,0,0,0}; o[mt][1] = (f32x4){0,0,0,0}; }
    const uint* Pw = (const uint*)Pbuf;         // dword units, row stride 33
    const uint* Vw = (const uint*)VTbuf;
#pragma unroll
    for (int ks = 0; ks < 2; ++ks) {
        short8 ap[4];
#pragma unroll
        for (int mt = 0; mt < 4; ++mt) {
            int base = (mt * 16 + r16) * 33 + ks * 16 + q * 4;
            uint d0 = Pw[base], d1 = Pw[base + 1], d2 = Pw[base + 2], d3 = Pw[base + 3];
            union { uint u[4]; short8 s8; } cv; cv.u[0] = d0; cv.u[1] = d1; cv.u[2] = d2; cv.u[3] = d3;
            ap[mt] = cv.s8;
        }
        short8 bv[2];
#pragma unroll
        for (int nt = 0; nt < 2; ++nt) {
            int base = (nt * 16 + r16) * 33 + ks * 16 + q * 4;
            uint d0 = Vw[base], d1 = Vw[base + 1], d2 = Vw[base + 2], d3 = Vw[base + 3];
            union { uint u[4]; short8 s8; } cv; cv.u[0] = d0; cv.u[1] = d1; cv.u[2] = d2; cv.u[3] = d3;
            bv[nt] = cv.s8;
        }
#pragma unroll
        for (int mt = 0; mt < 4; ++mt)
#pragma unroll
            for (int nt = 0; nt < 2; ++nt)
                o[mt][nt] = __builtin_amdgcn_mfma_f32_16x16x32_bf16(ap[mt], bv[nt], o[mt][nt], 0, 0, 0);
    }
    __syncthreads();   // fence: P uint-reads complete before Of float-overwrite (TBAA WAR)

    float* Of = (float*)Pbuf;                   // row stride 33 dwords
#pragma unroll
    for (int mt = 0; mt < 4; ++mt)
#pragma unroll
        for (int rg = 0; rg < 4; ++rg) {
            int i = mt * 16 + q * 4 + rg;
            float sc = rinv[mt][rg];
            Of[i * 33 + r16]      = o[mt][0][rg] * sc;
            Of[i * 33 + 16 + r16] = o[mt][1][rg] * sc;
        }
    __syncthreads();   // fence: Of writes before cross-lane reads
    {
        int pix = wpix(wh, ww, lane);
        ushort* ob = (ushort*)attnout + (size_t)(b * HW + pix) * 128 + head * 32;
#pragma unroll
        for (int g = 0; g < 4; ++g) {
            short8 o8;
#pragma unroll
            for (int e = 0; e < 8; ++e) o8[e] = (short)(ushort)f2bf(Of[lane * 33 + g * 8 + e]);
            *(short8*)(ob + g * 8) = o8;
        }
    }
}

// ---------------------------------------------------------------- launch
extern "C" void kernel_launch(void* const* d_in, const int* in_sizes, int n_in,
                              void* d_out, int out_size, void* d_ws, size_t ws_size,
                              hipStream_t stream)
{
    const float* x     = (const float*)d_in[0];
    const float* cg_s  = (const float*)d_in[1];
    const float* cg_b  = (const float*)d_in[2];
    const float* pw1_w = (const float*)d_in[3];
    const float* pw1_b = (const float*)d_in[4];
    const float* dw_w  = (const float*)d_in[5];
    const float* dw_b  = (const float*)d_in[6];
    const float* pw2_w = (const float*)d_in[7];
    const float* pw2_b = (const float*)d_in[8];
    const float* beta  = (const float*)d_in[9];
    const float* at_s  = (const float*)d_in[10];
    const float* at_b  = (const float*)d_in[11];
    const float* qkv_w = (const float*)d_in[12];
    const float* qkv_b = (const float*)d_in[13];
    const float* rpe   = (const float*)d_in[14];
    const float* proj_w= (const float*)d_in[15];
    const float* proj_b= (const float*)d_in[16];
    const float* alpha = (const float*)d_in[17];
    const float* ff_s  = (const float*)d_in[18];
    const float* ff_b  = (const float*)d_in[19];
    const float* fc1_w = (const float*)d_in[20];
    const float* fc1_b = (const float*)d_in[21];
    const float* fc2_w = (const float*)d_in[22];
    const float* fc2_b = (const float*)d_in[23];
    const float* gamma = (const float*)d_in[24];
    float* out = (float*)d_out;

    char* ws = (char*)d_ws;
    __hip_bfloat16* Xn    = (__hip_bfloat16*)ws;
    __hip_bfloat16* t1    = (__hip_bfloat16*)(ws + 18874368);
    __hip_bfloat16* qkvb  = t1;
    __hip_bfloat16* tg    = (__hip_bfloat16*)(ws + 94371840);
    __hip_bfloat16* attno = tg;
    char* wsw = ws + 132120576;
    ushort* w1b  = (ushort*)(wsw);             // 512*128
    ushort* w2b  = (ushort*)(wsw + 131072);    // 128*256
    ushort* wqb  = (ushort*)(wsw + 196608);    // 384*128
    ushort* wpb  = (ushort*)(wsw + 294912);    // 128*128
    ushort* wf1b = (ushort*)(wsw + 327680);    // 512*128 (paired u/v)
    ushort* wf2b = (ushort*)(wsw + 458752);    // 128*256
    float*  dwt  = (float*) (wsw + 524288);    // 9*512 fp32
    float*  bg1  = (float*) (wsw + 542720);    // 512 fp32 (paired fc1 bias)

    wconv_kernel<<<1044, 256, 0, stream>>>(pw1_w, pw2_w, qkv_w, proj_w, fc1_w, fc2_w, dw_w, fc1_b,
                                           w1b, w2b, wqb, wpb, wf1b, wf2b, dwt, bg1);

    // ---- stage 1: conv_gated_block (pw2 fuses residual + at-RMSNorm)
    rmsnorm_t_kernel<<<288, 256, 0, stream>>>(x, cg_s, cg_b, Xn);
    gemm_kernel<128, 0><<<dim3(576, 4), 256, 0, stream>>>(Xn, (__hip_bfloat16*)w1b, pw1_b, 512, t1,
                                                          nullptr, nullptr, nullptr, nullptr, nullptr, nullptr);
    dwgate_kernel<<<dim3(1152, 4), 256, 0, stream>>>(t1, dwt, dw_b, tg);
    gemm_kernel<256, 3><<<dim3(576, 1), 256, 0, stream>>>(tg, (__hip_bfloat16*)w2b, pw2_b, 128, nullptr,
                                                          x, out, beta, at_s, at_b, Xn);

    // ---- stage 2: window attention (proj fuses residual + ff-RMSNorm)
    gemm_kernel<128, 0><<<dim3(576, 3), 256, 0, stream>>>(Xn, (__hip_bfloat16*)wqb, qkv_b, 384, qkvb,
                                                          nullptr, nullptr, nullptr, nullptr, nullptr, nullptr);
    attn_kernel<<<dim3(576, 2), 256, 0, stream>>>(qkvb, rpe, attno);
    gemm_kernel<128, 3><<<dim3(576, 1), 256, 0, stream>>>(attno, (__hip_bfloat16*)wpb, proj_b, 128, nullptr,
                                                          out, out, alpha, ff_s, ff_b, Xn);

    // ---- stage 3: gated FFN (gate fused into fc1 GEMM epilogue)
    gemm_kernel<128, 2><<<dim3(576, 4), 256, 0, stream>>>(Xn, (__hip_bfloat16*)wf1b, bg1, 512, tg,
                                                          nullptr, nullptr, nullptr, nullptr, nullptr, nullptr);
    gemm_kernel<256, 1><<<dim3(576, 1), 256, 0, stream>>>(tg, (__hip_bfloat16*)wf2b, fc2_b, 128, nullptr,
                                                          out, out, gamma, nullptr, nullptr, nullptr);
}

// Round 9
// 396.707 us; speedup vs baseline: 1.1667x; 1.1667x over previous
//
#include <hip/hip_runtime.h>
#include <hip/hip_bf16.h>
#include <math.h>

#define HW   36864        // 192*192
#define BHW  73728        // 2*HW

typedef float f32x4 __attribute__((ext_vector_type(4)));
typedef short short8 __attribute__((ext_vector_type(8)));

__device__ __forceinline__ unsigned f2bf(float f) {        // fp32 -> bf16 bits, RNE
    unsigned u = __float_as_uint(f);
    return (u + 0x7fffu + ((u >> 16) & 1u)) >> 16;
}
__device__ __forceinline__ float bf2f(unsigned short s) {  // bf16 bits -> fp32
    return __uint_as_float(((unsigned)s) << 16);
}
__device__ __forceinline__ float gelu_erf(float v) {
    return v * 0.5f * (1.0f + erff(v * 0.70710678118654752f));
}

// ---------------------------------------------------------------- weight prep
// fc1 weights/bias PAIRED: col 2c = u-channel c, col 2c+1 = v-channel c (fused gate epilogue).
__global__ __launch_bounds__(256)
void wconv_kernel(const float* __restrict__ w1, const float* __restrict__ w2,
                  const float* __restrict__ wq, const float* __restrict__ wp,
                  const float* __restrict__ wf1, const float* __restrict__ wf2,
                  const float* __restrict__ dww, const float* __restrict__ fb1,
                  ushort* __restrict__ o1, ushort* __restrict__ o2, ushort* __restrict__ oq,
                  ushort* __restrict__ op, ushort* __restrict__ of1, ushort* __restrict__ of2,
                  float* __restrict__ dwt, float* __restrict__ bg)
{
    int i = blockIdx.x * 256 + threadIdx.x;
    if      (i <  65536) o1 [i         ] = (ushort)f2bf(w1 [i         ]);
    else if (i <  98304) o2 [i -  65536] = (ushort)f2bf(w2 [i -  65536]);
    else if (i < 147456) oq [i -  98304] = (ushort)f2bf(wq [i -  98304]);
    else if (i < 163840) op [i - 147456] = (ushort)f2bf(wp [i - 147456]);
    else if (i < 229376) {
        int j = i - 163840;            // paired fc1: col=j>>7, k=j&127
        int col = j >> 7, k = j & 127;
        of1[j] = (ushort)f2bf(wf1[((size_t)((col & 1) * 256 + (col >> 1))) * 128 + k]);
    }
    else if (i < 262144) of2[i - 229376] = (ushort)f2bf(wf2[i - 229376]);
    else if (i < 266752) {
        int j = i - 262144;            // j = tap*512 + c
        int tap = j >> 9, c = j & 511;
        dwt[j] = dww[c * 9 + tap];
    }
    else if (i < 267264) {
        int j = i - 266752;            // paired fc1 bias
        bg[j] = fb1[(j & 1) * 256 + (j >> 1)];
    }
}

// ---------------------------------------------------------------- rmsnorm (NCHW fp32 -> pixel-major bf16)
__global__ __launch_bounds__(256)
void rmsnorm_t_kernel(const float* __restrict__ src, const float* __restrict__ s,
                      const float* __restrict__ bi, __hip_bfloat16* __restrict__ dst)
{
    int P = blockIdx.x * 256 + threadIdx.x;          // pixel id in [0, BHW)
    int b = P / HW, pp = P - b * HW;
    const float* xb = src + (size_t)b * 128 * HW + pp;
    float ss = 0.f;
#pragma unroll 8
    for (int c = 0; c < 128; ++c) { float v = xb[(size_t)c * HW]; ss = fmaf(v, v, ss); }
    float inv = 1.0f / sqrtf(ss * 0.0078125f + 1e-6f);
    unsigned* drow = (unsigned*)(dst + (size_t)P * 128);
#pragma unroll 4
    for (int c = 0; c < 128; c += 2) {
        float v0 = fmaf(s[c]     * xb[(size_t)c * HW],       inv, bi[c]);
        float v1 = fmaf(s[c + 1] * xb[(size_t)(c + 1) * HW], inv, bi[c + 1]);
        drow[c >> 1] = f2bf(v0) | (f2bf(v1) << 16);
    }
}

// ---------------------------------------------------------------- MFMA GEMM (128x128 tile), round-6 epilogues
// MODE 0: store bf16 pixel-major (BHW,N), direct scalar stores.
// MODE 2: N==512 paired u/v cols; store u*gelu(v) bf16 (BHW,256) via shfl pairing.
template<int K, int MODE>
__global__ __launch_bounds__(256)
void gemm_kernel(const __hip_bfloat16* __restrict__ Abf, const __hip_bfloat16* __restrict__ Wbf,
                 const float* __restrict__ bias, int N,
                 __hip_bfloat16* __restrict__ outb)
{
    __shared__ char smem[16384];
    short* sA = (short*)smem;
    short* sB = sA + 4096;

    const short* A = (const short*)Abf;
    const short* W = (const short*)Wbf;

    int t = threadIdx.x;
    int lane = t & 63, wv = t >> 6;
    int wm = wv & 1, wn = wv >> 1;
    int m0 = blockIdx.x * 128;
    int n0 = blockIdx.y * 128;
    int q = lane >> 4, r16 = lane & 15;

    f32x4 acc[4][4];
#pragma unroll
    for (int nt = 0; nt < 4; ++nt) {
        float bv = bias[n0 + wn * 64 + nt * 16 + r16];
#pragma unroll
        for (int mt = 0; mt < 4; ++mt) acc[mt][nt] = (f32x4){bv, bv, bv, bv};
    }

    for (int kk = 0; kk < K; kk += 32) {
#pragma unroll
        for (int i = 0; i < 2; ++i) {
            int rbase = wv * 32 + i * 16;
            int row = rbase + (lane >> 2);
            int kc = (lane & 3) ^ ((row >> 1) & 3);
            const short* ga = A + (size_t)(m0 + row) * K + kk + kc * 8;
            const short* gb = W + (size_t)(n0 + row) * K + kk + kc * 8;
            __builtin_amdgcn_global_load_lds((const __attribute__((address_space(1))) void*)ga,
                                             (__attribute__((address_space(3))) void*)(sA + rbase * 32), 16, 0, 0);
            __builtin_amdgcn_global_load_lds((const __attribute__((address_space(1))) void*)gb,
                                             (__attribute__((address_space(3))) void*)(sB + rbase * 32), 16, 0, 0);
        }
        __syncthreads();

        short8 af[4], bf[4];
#pragma unroll
        for (int mt = 0; mt < 4; ++mt) {
            int r = wm * 64 + mt * 16 + r16;
            af[mt] = *(const short8*)(sA + (r * 4 + (q ^ ((r >> 1) & 3))) * 8);
        }
#pragma unroll
        for (int nt = 0; nt < 4; ++nt) {
            int r = wn * 64 + nt * 16 + r16;
            bf[nt] = *(const short8*)(sB + (r * 4 + (q ^ ((r >> 1) & 3))) * 8);
        }
#pragma unroll
        for (int mt = 0; mt < 4; ++mt)
#pragma unroll
            for (int nt = 0; nt < 4; ++nt)
                acc[mt][nt] = __builtin_amdgcn_mfma_f32_16x16x32_bf16(af[mt], bf[nt], acc[mt][nt], 0, 0, 0);
        __syncthreads();
    }

    if constexpr (MODE == 0) {
        ushort* ob = (ushort*)outb;
#pragma unroll
        for (int mt = 0; mt < 4; ++mt) {
            int row0 = m0 + wm * 64 + mt * 16 + q * 4;
#pragma unroll
            for (int nt = 0; nt < 4; ++nt) {
                int col = n0 + wn * 64 + nt * 16 + r16;
#pragma unroll
                for (int rg = 0; rg < 4; ++rg)
                    ob[(size_t)(row0 + rg) * N + col] = (ushort)f2bf(acc[mt][nt][rg]);
            }
        }
    } else {   // MODE 2
        ushort* ob = (ushort*)outb;
        int parity = r16 & 1;
#pragma unroll
        for (int mt = 0; mt < 4; ++mt) {
            int row0 = m0 + wm * 64 + mt * 16 + q * 4;
#pragma unroll
            for (int nt = 0; nt < 4; ++nt) {
                int ch = (n0 + wn * 64 + nt * 16 + r16) >> 1;
#pragma unroll
                for (int rg = 0; rg < 4; ++rg) {
                    float val = acc[mt][nt][rg];
                    float part = __shfl_xor(val, 1);
                    float uu = parity ? part : val;
                    float vv = parity ? val : part;
                    float g = uu * gelu_erf(vv);
                    if (!parity)
                        ob[(size_t)(row0 + rg) * 256 + ch] = (ushort)f2bf(g);
                }
            }
        }
    }
}

// ---------------------------------------------------------------- MFMA GEMM, N=128, 64-row tile
// Grid 1152 (2x round-6) -> ~4.5 blocks/CU available; LDS <=39.4KB -> 4 blocks/CU.
// rdst(NCHW fp32) = rsrc + scale*C; RMS: also emits xn bf16 pixel-major (fused RMSNorm).
template<int K, bool RMS>
__global__ __launch_bounds__(256)
void gemm_n128_kernel(const __hip_bfloat16* __restrict__ Abf, const __hip_bfloat16* __restrict__ Wbf,
                      const float* __restrict__ bias,
                      const float* __restrict__ rsrc, float* __restrict__ rdst,
                      const float* __restrict__ scale,
                      const float* __restrict__ rms_s, const float* __restrict__ rms_b,
                      __hip_bfloat16* __restrict__ xn)
{
    constexpr int SMEM = RMS ? 39424 : 34816;
    __shared__ char smem[SMEM];
    short* sA = (short*)smem;                 // 64 rows x 32k = 4KB
    short* sB = sA + 2048;                    // 128 rows x 32k = 8KB
    float* sEp = (float*)smem;                // [128 ch][68 px] = 34816 (overlays staging)
    float* sPar = (float*)(smem + 34816);     // RMS: [64 px][17]
    float* sInv = (float*)(smem + 39168);     // RMS: [64 px]

    const short* A = (const short*)Abf;
    const short* W = (const short*)Wbf;

    int t = threadIdx.x;
    int lane = t & 63, wv = t >> 6;
    int m0 = blockIdx.x * 64;
    int q = lane >> 4, r16 = lane & 15;

    f32x4 acc[4][2];
#pragma unroll
    for (int nt = 0; nt < 2; ++nt) {
        float bv = bias[wv * 32 + nt * 16 + r16];
#pragma unroll
        for (int mt = 0; mt < 4; ++mt) acc[mt][nt] = (f32x4){bv, bv, bv, bv};
    }

    for (int kk = 0; kk < K; kk += 32) {
        {   // A: wave wv stages rows wv*16 .. +16
            int rbase = wv * 16;
            int row = rbase + (lane >> 2);
            int kc = (lane & 3) ^ ((row >> 1) & 3);
            const short* ga = A + (size_t)(m0 + row) * K + kk + kc * 8;
            __builtin_amdgcn_global_load_lds((const __attribute__((address_space(1))) void*)ga,
                                             (__attribute__((address_space(3))) void*)(sA + rbase * 32), 16, 0, 0);
        }
#pragma unroll
        for (int i = 0; i < 2; ++i) {   // B: wave wv stages channel rows wv*32 .. +32
            int rbase = wv * 32 + i * 16;
            int row = rbase + (lane >> 2);
            int kc = (lane & 3) ^ ((row >> 1) & 3);
            const short* gb = W + (size_t)row * K + kk + kc * 8;
            __builtin_amdgcn_global_load_lds((const __attribute__((address_space(1))) void*)gb,
                                             (__attribute__((address_space(3))) void*)(sB + rbase * 32), 16, 0, 0);
        }
        __syncthreads();

        short8 af[4], bf[2];
#pragma unroll
        for (int mt = 0; mt < 4; ++mt) {
            int r = mt * 16 + r16;
            af[mt] = *(const short8*)(sA + (r * 4 + (q ^ ((r >> 1) & 3))) * 8);
        }
#pragma unroll
        for (int nt = 0; nt < 2; ++nt) {
            int r = wv * 32 + nt * 16 + r16;
            bf[nt] = *(const short8*)(sB + (r * 4 + (q ^ ((r >> 1) & 3))) * 8);
        }
#pragma unroll
        for (int mt = 0; mt < 4; ++mt)
#pragma unroll
            for (int nt = 0; nt < 2; ++nt)
                acc[mt][nt] = __builtin_amdgcn_mfma_f32_16x16x32_bf16(af[mt], bf[nt], acc[mt][nt], 0, 0, 0);
        __syncthreads();
    }

    // single-pass epilogue: all 4 waves write their C fragments
#pragma unroll
    for (int mt = 0; mt < 4; ++mt)
#pragma unroll
        for (int nt = 0; nt < 2; ++nt) {
            int c = wv * 32 + nt * 16 + r16;
            int px = mt * 16 + q * 4;
#pragma unroll
            for (int rg = 0; rg < 4; ++rg)
                sEp[c * 68 + px + rg] = acc[mt][nt][rg];
        }
    __syncthreads();

    int c16 = t >> 4, l16 = t & 15;
    int p0 = m0 + l16 * 4;
    int b = p0 / HW, pp = p0 - b * HW;
    float sc = scale[0];
    f32x4 ov[8];
    f32x4 ps = (f32x4){0.f, 0.f, 0.f, 0.f};
#pragma unroll
    for (int i = 0; i < 8; ++i) {
        int c = c16 + i * 16;
        f32x4 v = *(const f32x4*)&sEp[c * 68 + l16 * 4];
        size_t gi = (size_t)(b * 128 + c) * HW + pp;
        f32x4 r = *(const f32x4*)&rsrc[gi];
        f32x4 o = r + sc * v;
        *(f32x4*)&rdst[gi] = o;
        if constexpr (RMS) {
            ov[i] = o;
#pragma unroll
            for (int rg = 0; rg < 4; ++rg) ps[rg] = fmaf(o[rg], o[rg], ps[rg]);
        }
    }
    if constexpr (RMS) {
#pragma unroll
        for (int rg = 0; rg < 4; ++rg) sPar[(l16 * 4 + rg) * 17 + c16] = ps[rg];
        __syncthreads();               // also fences sEp reads before sXn overlay
        if (t < 64) {
            float ssum = 0.f;
#pragma unroll
            for (int j = 0; j < 16; ++j) ssum += sPar[t * 17 + j];
            sInv[t] = 1.0f / sqrtf(ssum * 0.0078125f + 1e-6f);
        }
        __syncthreads();
        float iv[4];
#pragma unroll
        for (int rg = 0; rg < 4; ++rg) iv[rg] = sInv[l16 * 4 + rg];
        ushort* sXn = (ushort*)smem;   // overlay dead sEp: [64 px][132 ch-pad]
#pragma unroll
        for (int i = 0; i < 8; ++i) {
            int c = c16 + i * 16;
            float scs = rms_s[c], bcs = rms_b[c];
#pragma unroll
            for (int rg = 0; rg < 4; ++rg)
                sXn[(l16 * 4 + rg) * 132 + c] = (ushort)f2bf(fmaf(scs * ov[i][rg], iv[rg], bcs));
        }
        __syncthreads();
        {
            int px = t >> 2, qd = t & 3;
            const ushort* src = sXn + px * 132 + qd * 32;
            ushort* dst = (ushort*)xn + (size_t)(m0 + px) * 128 + qd * 32;
#pragma unroll
            for (int g = 0; g < 4; ++g)
                *(short8*)(dst + g * 8) = *(const short8*)(src + g * 8);
        }
    }
}

// ---------------------------------------------------------------- dwconv3x3 + gate, V=2 register-blocked (round-6)
__global__ __launch_bounds__(256)
void dwgate_kernel(const __hip_bfloat16* __restrict__ t1, const float* __restrict__ dwt,
                   const float* __restrict__ dwb, __hip_bfloat16* __restrict__ tg)
{
    int t = threadIdx.x;
    int c8 = t & 31, pxl = t >> 5;
    int bx = blockIdx.x;
    int wseg = bx % 24; int tmp = bx / 24;
    int hp2 = tmp % 96; int b = tmp / 96;
    int h0 = hp2 * 2, w = wseg * 8 + pxl;
    int cu = c8 * 8;
    const ushort* t1u = (const ushort*)t1;

    float au[2][8], av[2][8];
    {
        f32x4 b0 = *(const f32x4*)(dwb + cu);
        f32x4 b1 = *(const f32x4*)(dwb + cu + 4);
        f32x4 b2 = *(const f32x4*)(dwb + 256 + cu);
        f32x4 b3 = *(const f32x4*)(dwb + 256 + cu + 4);
#pragma unroll
        for (int e = 0; e < 4; ++e) {
            au[0][e] = au[1][e] = b0[e]; au[0][e + 4] = au[1][e + 4] = b1[e];
            av[0][e] = av[1][e] = b2[e]; av[0][e + 4] = av[1][e + 4] = b3[e];
        }
    }
#pragma unroll
    for (int r = 0; r < 4; ++r) {                    // tap row h0-1+r
        int hh = h0 - 1 + r;
        if (hh < 0 || hh >= 192) continue;
#pragma unroll
        for (int dxi = 0; dxi < 3; ++dxi) {
            int w2 = w + dxi - 1;
            if (w2 < 0 || w2 >= 192) continue;
            const ushort* urow = t1u + (size_t)(b * HW + hh * 192 + w2) * 512 + cu;
            short8 u8 = *(const short8*)urow;
            short8 v8 = *(const short8*)(urow + 256);
#pragma unroll
            for (int py = 0; py < 2; ++py) {
                int dy = r - 1 - py;                 // compile-time after unroll
                if (dy < -1 || dy > 1) continue;
                int tap = (dy + 1) * 3 + dxi;
                f32x4 wu0 = *(const f32x4*)(dwt + tap * 512 + cu);
                f32x4 wu1 = *(const f32x4*)(dwt + tap * 512 + cu + 4);
                f32x4 wv0 = *(const f32x4*)(dwt + tap * 512 + 256 + cu);
                f32x4 wv1 = *(const f32x4*)(dwt + tap * 512 + 256 + cu + 4);
#pragma unroll
                for (int e = 0; e < 4; ++e) {
                    au[py][e]     = fmaf(wu0[e], bf2f((ushort)u8[e]),     au[py][e]);
                    au[py][e + 4] = fmaf(wu1[e], bf2f((ushort)u8[e + 4]), au[py][e + 4]);
                    av[py][e]     = fmaf(wv0[e], bf2f((ushort)v8[e]),     av[py][e]);
                    av[py][e + 4] = fmaf(wv1[e], bf2f((ushort)v8[e + 4]), av[py][e + 4]);
                }
            }
        }
    }
#pragma unroll
    for (int py = 0; py < 2; ++py) {
        short8 o8;
#pragma unroll
        for (int e = 0; e < 8; ++e) o8[e] = (short)(ushort)f2bf(au[py][e] * gelu_erf(av[py][e]));
        int gp = b * HW + (h0 + py) * 192 + w;
        *(short8*)((ushort*)tg + (size_t)gp * 256 + cu) = o8;
    }
}

// ---------------------------------------------------------------- windowed attention (MFMA)
__device__ __forceinline__ int wpix(int wh, int ww, int m) {
    int ty = m >> 3, tx = m & 7;
    int hs = wh * 8 + ty + 4; if (hs >= 192) hs -= 192;
    int wsc = ww * 8 + tx + 4; if (wsc >= 192) wsc -= 192;
    return hs * 192 + wsc;
}
__device__ __forceinline__ int wreg(int wh, int ww, int m) {   // shift-mask region id
    int hr = wh * 8 + (m >> 3), wr = ww * 8 + (m & 7);
    return ((hr < 184) ? 0 : (hr < 188) ? 1 : 2) * 3 +
           ((wr < 184) ? 0 : (wr < 188) ? 1 : 2);
}

__global__ __launch_bounds__(256)
void attn_kernel(const __hip_bfloat16* __restrict__ qkv, const float* __restrict__ rpe,
                 __hip_bfloat16* __restrict__ attnout)
{
    __shared__ char smem[54288];
    int t = threadIdx.x;
    int lane = t & 63, head = t >> 6;
    int wh = blockIdx.x / 24, ww = blockIdx.x % 24;
    int b = blockIdx.y;
    int q = lane >> 4, r16 = lane & 15;

    float* rpe_s = (float*)(smem + 50688);
    for (int i = t; i < 900; i += 256) rpe_s[i] = rpe[i];

    char* Pbuf  = smem + head * 12672;
    char* VTbuf = Pbuf + 8448;
    const ushort* qkvu = (const ushort*)qkv;

    short8 aq[4], bk[4];
#pragma unroll
    for (int mt = 0; mt < 4; ++mt) {
        int pix = wpix(wh, ww, mt * 16 + r16);
        const ushort* rowp = qkvu + (size_t)(b * HW + pix) * 384 + head * 32 + q * 8;
        aq[mt] = *(const short8*)rowp;
        bk[mt] = *(const short8*)(rowp + 128);
    }
    {
        int pix = wpix(wh, ww, lane);
        const ushort* vp = qkvu + (size_t)(b * HW + pix) * 384 + 256 + head * 32;
        ushort* vt = (ushort*)VTbuf;           // VT[d][j]: row stride 66 ushorts
#pragma unroll
        for (int g = 0; g < 4; ++g) {
            short8 v8 = *(const short8*)(vp + g * 8);
#pragma unroll
            for (int e = 0; e < 8; ++e) vt[(g * 8 + e) * 66 + lane] = (ushort)v8[e];
        }
    }
    __syncthreads();

    f32x4 s[4][4];
#pragma unroll
    for (int mt = 0; mt < 4; ++mt)
#pragma unroll
        for (int nt = 0; nt < 4; ++nt) s[mt][nt] = (f32x4){0.f, 0.f, 0.f, 0.f};
#pragma unroll
    for (int mt = 0; mt < 4; ++mt)
#pragma unroll
        for (int nt = 0; nt < 4; ++nt)
            s[mt][nt] = __builtin_amdgcn_mfma_f32_16x16x32_bf16(aq[mt], bk[nt], s[mt][nt], 0, 0, 0);

    bool edge = (wh == 23) || (ww == 23);
    int tyj[4], txj[4], rgj[4];
#pragma unroll
    for (int nt = 0; nt < 4; ++nt) {
        int j = nt * 16 + r16;
        tyj[nt] = j >> 3; txj[nt] = j & 7;
        rgj[nt] = wreg(wh, ww, j);
    }
    float rinv[4][4];
#pragma unroll
    for (int mt = 0; mt < 4; ++mt) {
#pragma unroll
        for (int rg = 0; rg < 4; ++rg) {
            int i = mt * 16 + q * 4 + rg;
            int tyi = i >> 3, txi = i & 7;
            int rgi = edge ? wreg(wh, ww, i) : 0;
            float mx = -INFINITY;
#pragma unroll
            for (int nt = 0; nt < 4; ++nt) {
                float v = s[mt][nt][rg] * 0.17677669529663689f
                        + rpe_s[((tyi - tyj[nt] + 7) * 15 + (txi - txj[nt] + 7)) * 4 + head];
                if (edge && rgi != rgj[nt]) v = -INFINITY;
                s[mt][nt][rg] = v;
                mx = fmaxf(mx, v);
            }
            mx = fmaxf(mx, __shfl_xor(mx, 1));
            mx = fmaxf(mx, __shfl_xor(mx, 2));
            mx = fmaxf(mx, __shfl_xor(mx, 4));
            mx = fmaxf(mx, __shfl_xor(mx, 8));
            float sum = 0.f;
#pragma unroll
            for (int nt = 0; nt < 4; ++nt) {
                float e = __expf(s[mt][nt][rg] - mx);
                s[mt][nt][rg] = e;
                sum += e;
            }
            sum += __shfl_xor(sum, 1);
            sum += __shfl_xor(sum, 2);
            sum += __shfl_xor(sum, 4);
            sum += __shfl_xor(sum, 8);
            rinv[mt][rg] = 1.0f / sum;
        }
    }

    ushort* Pu = (ushort*)Pbuf;                 // row stride 66 ushorts
#pragma unroll
    for (int mt = 0; mt < 4; ++mt)
#pragma unroll
        for (int rg = 0; rg < 4; ++rg) {
            int i = mt * 16 + q * 4 + rg;
#pragma unroll
            for (int nt = 0; nt < 4; ++nt)
                Pu[i * 66 + nt * 16 + r16] = (ushort)f2bf(s[mt][nt][rg]);
        }
    __syncthreads();   // fence: P ushort-writes before uint-reads (TBAA)

    f32x4 o[4][2];
#pragma unroll
    for (int mt = 0; mt < 4; ++mt) { o[mt][0] = (f32x4){0,0,0,0}; o[mt][1] = (f32x4){0,0,0,0}; }
    const uint* Pw = (const uint*)Pbuf;         // dword units, row stride 33
    const uint* Vw = (const uint*)VTbuf;
#pragma unroll
    for (int ks = 0; ks < 2; ++ks) {
        short8 ap[4];
#pragma unroll
        for (int mt = 0; mt < 4; ++mt) {
            int base = (mt * 16 + r16) * 33 + ks * 16 + q * 4;
            uint d0 = Pw[base], d1 = Pw[base + 1], d2 = Pw[base + 2], d3 = Pw[base + 3];
            union { uint u[4]; short8 s8; } cv; cv.u[0] = d0; cv.u[1] = d1; cv.u[2] = d2; cv.u[3] = d3;
            ap[mt] = cv.s8;
        }
        short8 bv[2];
#pragma unroll
        for (int nt = 0; nt < 2; ++nt) {
            int base = (nt * 16 + r16) * 33 + ks * 16 + q * 4;
            uint d0 = Vw[base], d1 = Vw[base + 1], d2 = Vw[base + 2], d3 = Vw[base + 3];
            union { uint u[4]; short8 s8; } cv; cv.u[0] = d0; cv.u[1] = d1; cv.u[2] = d2; cv.u[3] = d3;
            bv[nt] = cv.s8;
        }
#pragma unroll
        for (int mt = 0; mt < 4; ++mt)
#pragma unroll
            for (int nt = 0; nt < 2; ++nt)
                o[mt][nt] = __builtin_amdgcn_mfma_f32_16x16x32_bf16(ap[mt], bv[nt], o[mt][nt], 0, 0, 0);
    }
    __syncthreads();   // fence: P uint-reads complete before Of float-overwrite (TBAA WAR)

    float* Of = (float*)Pbuf;                   // row stride 33 dwords
#pragma unroll
    for (int mt = 0; mt < 4; ++mt)
#pragma unroll
        for (int rg = 0; rg < 4; ++rg) {
            int i = mt * 16 + q * 4 + rg;
            float sc = rinv[mt][rg];
            Of[i * 33 + r16]      = o[mt][0][rg] * sc;
            Of[i * 33 + 16 + r16] = o[mt][1][rg] * sc;
        }
    __syncthreads();   // fence: Of writes before cross-lane reads
    {
        int pix = wpix(wh, ww, lane);
        ushort* ob = (ushort*)attnout + (size_t)(b * HW + pix) * 128 + head * 32;
#pragma unroll
        for (int g = 0; g < 4; ++g) {
            short8 o8;
#pragma unroll
            for (int e = 0; e < 8; ++e) o8[e] = (short)(ushort)f2bf(Of[lane * 33 + g * 8 + e]);
            *(short8*)(ob + g * 8) = o8;
        }
    }
}

// ---------------------------------------------------------------- launch
extern "C" void kernel_launch(void* const* d_in, const int* in_sizes, int n_in,
                              void* d_out, int out_size, void* d_ws, size_t ws_size,
                              hipStream_t stream)
{
    const float* x     = (const float*)d_in[0];
    const float* cg_s  = (const float*)d_in[1];
    const float* cg_b  = (const float*)d_in[2];
    const float* pw1_w = (const float*)d_in[3];
    const float* pw1_b = (const float*)d_in[4];
    const float* dw_w  = (const float*)d_in[5];
    const float* dw_b  = (const float*)d_in[6];
    const float* pw2_w = (const float*)d_in[7];
    const float* pw2_b = (const float*)d_in[8];
    const float* beta  = (const float*)d_in[9];
    const float* at_s  = (const float*)d_in[10];
    const float* at_b  = (const float*)d_in[11];
    const float* qkv_w = (const float*)d_in[12];
    const float* qkv_b = (const float*)d_in[13];
    const float* rpe   = (const float*)d_in[14];
    const float* proj_w= (const float*)d_in[15];
    const float* proj_b= (const float*)d_in[16];
    const float* alpha = (const float*)d_in[17];
    const float* ff_s  = (const float*)d_in[18];
    const float* ff_b  = (const float*)d_in[19];
    const float* fc1_w = (const float*)d_in[20];
    const float* fc1_b = (const float*)d_in[21];
    const float* fc2_w = (const float*)d_in[22];
    const float* fc2_b = (const float*)d_in[23];
    const float* gamma = (const float*)d_in[24];
    float* out = (float*)d_out;

    char* ws = (char*)d_ws;
    __hip_bfloat16* Xn    = (__hip_bfloat16*)ws;
    __hip_bfloat16* t1    = (__hip_bfloat16*)(ws + 18874368);
    __hip_bfloat16* qkvb  = t1;
    __hip_bfloat16* tg    = (__hip_bfloat16*)(ws + 94371840);
    __hip_bfloat16* attno = tg;
    char* wsw = ws + 132120576;
    ushort* w1b  = (ushort*)(wsw);             // 512*128
    ushort* w2b  = (ushort*)(wsw + 131072);    // 128*256
    ushort* wqb  = (ushort*)(wsw + 196608);    // 384*128
    ushort* wpb  = (ushort*)(wsw + 294912);    // 128*128
    ushort* wf1b = (ushort*)(wsw + 327680);    // 512*128 (paired u/v)
    ushort* wf2b = (ushort*)(wsw + 458752);    // 128*256
    float*  dwt  = (float*) (wsw + 524288);    // 9*512 fp32
    float*  bg1  = (float*) (wsw + 542720);    // 512 fp32 (paired fc1 bias)

    wconv_kernel<<<1044, 256, 0, stream>>>(pw1_w, pw2_w, qkv_w, proj_w, fc1_w, fc2_w, dw_w, fc1_b,
                                           w1b, w2b, wqb, wpb, wf1b, wf2b, dwt, bg1);

    // ---- stage 1: conv_gated_block (pw2 fuses residual + at-RMSNorm)
    rmsnorm_t_kernel<<<288, 256, 0, stream>>>(x, cg_s, cg_b, Xn);
    gemm_kernel<128, 0><<<dim3(576, 4), 256, 0, stream>>>(Xn, (__hip_bfloat16*)w1b, pw1_b, 512, t1);
    dwgate_kernel<<<4608, 256, 0, stream>>>(t1, dwt, dw_b, tg);
    gemm_n128_kernel<256, true><<<1152, 256, 0, stream>>>(tg, (__hip_bfloat16*)w2b, pw2_b,
                                                          x, out, beta, at_s, at_b, Xn);

    // ---- stage 2: window attention (proj fuses residual + ff-RMSNorm)
    gemm_kernel<128, 0><<<dim3(576, 3), 256, 0, stream>>>(Xn, (__hip_bfloat16*)wqb, qkv_b, 384, qkvb);
    attn_kernel<<<dim3(576, 2), 256, 0, stream>>>(qkvb, rpe, attno);
    gemm_n128_kernel<128, true><<<1152, 256, 0, stream>>>(attno, (__hip_bfloat16*)wpb, proj_b,
                                                          out, out, alpha, ff_s, ff_b, Xn);

    // ---- stage 3: gated FFN (gate fused into fc1 GEMM epilogue)
    gemm_kernel<128, 2><<<dim3(576, 4), 256, 0, stream>>>(Xn, (__hip_bfloat16*)wf1b, bg1, 512, tg);
    gemm_n128_kernel<256, false><<<1152, 256, 0, stream>>>(tg, (__hip_bfloat16*)wf2b, fc2_b,
                                                           out, out, gamma, nullptr, nullptr, nullptr);
}

// Round 10
// 395.990 us; speedup vs baseline: 1.1688x; 1.0018x over previous
//
#include <hip/hip_runtime.h>
#include <hip/hip_bf16.h>
#include <math.h>

#define HW   36864        // 192*192
#define BHW  73728        // 2*HW

typedef float f32x4 __attribute__((ext_vector_type(4)));
typedef short short8 __attribute__((ext_vector_type(8)));
typedef short s16x4 __attribute__((ext_vector_type(4)));   // NB: 'short4' is a HIP built-in type

__device__ __forceinline__ unsigned f2bf(float f) {        // fp32 -> bf16 bits, RNE
    unsigned u = __float_as_uint(f);
    return (u + 0x7fffu + ((u >> 16) & 1u)) >> 16;
}
__device__ __forceinline__ float bf2f(unsigned short s) {  // bf16 bits -> fp32
    return __uint_as_float(((unsigned)s) << 16);
}
__device__ __forceinline__ float gelu_erf(float v) {
    return v * 0.5f * (1.0f + erff(v * 0.70710678118654752f));
}

// ---------------------------------------------------------------- weight prep
// fc1 weights/bias PAIRED: col 2c = u-channel c, col 2c+1 = v-channel c (fused gate epilogue).
__global__ __launch_bounds__(256)
void wconv_kernel(const float* __restrict__ w1, const float* __restrict__ w2,
                  const float* __restrict__ wq, const float* __restrict__ wp,
                  const float* __restrict__ wf1, const float* __restrict__ wf2,
                  const float* __restrict__ dww, const float* __restrict__ fb1,
                  ushort* __restrict__ o1, ushort* __restrict__ o2, ushort* __restrict__ oq,
                  ushort* __restrict__ op, ushort* __restrict__ of1, ushort* __restrict__ of2,
                  float* __restrict__ dwt, float* __restrict__ bg)
{
    int i = blockIdx.x * 256 + threadIdx.x;
    if      (i <  65536) o1 [i         ] = (ushort)f2bf(w1 [i         ]);
    else if (i <  98304) o2 [i -  65536] = (ushort)f2bf(w2 [i -  65536]);
    else if (i < 147456) oq [i -  98304] = (ushort)f2bf(wq [i -  98304]);
    else if (i < 163840) op [i - 147456] = (ushort)f2bf(wp [i - 147456]);
    else if (i < 229376) {
        int j = i - 163840;            // paired fc1: col=j>>7, k=j&127
        int col = j >> 7, k = j & 127;
        of1[j] = (ushort)f2bf(wf1[((size_t)((col & 1) * 256 + (col >> 1))) * 128 + k]);
    }
    else if (i < 262144) of2[i - 229376] = (ushort)f2bf(wf2[i - 229376]);
    else if (i < 266752) {
        int j = i - 262144;            // j = tap*512 + c
        int tap = j >> 9, c = j & 511;
        dwt[j] = dww[c * 9 + tap];
    }
    else if (i < 267264) {
        int j = i - 266752;            // paired fc1 bias
        bg[j] = fb1[(j & 1) * 256 + (j >> 1)];
    }
}

// ---------------------------------------------------------------- rmsnorm (NCHW fp32 -> pixel-major bf16)
__global__ __launch_bounds__(256)
void rmsnorm_t_kernel(const float* __restrict__ src, const float* __restrict__ s,
                      const float* __restrict__ bi, __hip_bfloat16* __restrict__ dst)
{
    int P = blockIdx.x * 256 + threadIdx.x;          // pixel id in [0, BHW)
    int b = P / HW, pp = P - b * HW;
    const float* xb = src + (size_t)b * 128 * HW + pp;
    float ss = 0.f;
#pragma unroll 8
    for (int c = 0; c < 128; ++c) { float v = xb[(size_t)c * HW]; ss = fmaf(v, v, ss); }
    float inv = 1.0f / sqrtf(ss * 0.0078125f + 1e-6f);
    unsigned* drow = (unsigned*)(dst + (size_t)P * 128);
#pragma unroll 4
    for (int c = 0; c < 128; c += 2) {
        float v0 = fmaf(s[c]     * xb[(size_t)c * HW],       inv, bi[c]);
        float v1 = fmaf(s[c + 1] * xb[(size_t)(c + 1) * HW], inv, bi[c + 1]);
        drow[c >> 1] = f2bf(v0) | (f2bf(v1) << 16);
    }
}

// ---------------------------------------------------------------- MFMA GEMM (128x128 tile)
// MODE 0: store bf16 pixel-major (BHW,N), direct scalar stores.
// MODE 2: N==512 paired u/v cols; store u*gelu(v) bf16 (BHW,256) via shfl pairing.
template<int K, int MODE>
__global__ __launch_bounds__(256)
void gemm_kernel(const __hip_bfloat16* __restrict__ Abf, const __hip_bfloat16* __restrict__ Wbf,
                 const float* __restrict__ bias, int N,
                 __hip_bfloat16* __restrict__ outb)
{
    __shared__ char smem[16384];
    short* sA = (short*)smem;
    short* sB = sA + 4096;

    const short* A = (const short*)Abf;
    const short* W = (const short*)Wbf;

    int t = threadIdx.x;
    int lane = t & 63, wv = t >> 6;
    int wm = wv & 1, wn = wv >> 1;
    int m0 = blockIdx.x * 128;
    int n0 = blockIdx.y * 128;
    int q = lane >> 4, r16 = lane & 15;

    f32x4 acc[4][4];
#pragma unroll
    for (int nt = 0; nt < 4; ++nt) {
        float bv = bias[n0 + wn * 64 + nt * 16 + r16];
#pragma unroll
        for (int mt = 0; mt < 4; ++mt) acc[mt][nt] = (f32x4){bv, bv, bv, bv};
    }

    for (int kk = 0; kk < K; kk += 32) {
#pragma unroll
        for (int i = 0; i < 2; ++i) {
            int rbase = wv * 32 + i * 16;
            int row = rbase + (lane >> 2);
            int kc = (lane & 3) ^ ((row >> 1) & 3);
            const short* ga = A + (size_t)(m0 + row) * K + kk + kc * 8;
            const short* gb = W + (size_t)(n0 + row) * K + kk + kc * 8;
            __builtin_amdgcn_global_load_lds((const __attribute__((address_space(1))) void*)ga,
                                             (__attribute__((address_space(3))) void*)(sA + rbase * 32), 16, 0, 0);
            __builtin_amdgcn_global_load_lds((const __attribute__((address_space(1))) void*)gb,
                                             (__attribute__((address_space(3))) void*)(sB + rbase * 32), 16, 0, 0);
        }
        __syncthreads();

        short8 af[4], bf[4];
#pragma unroll
        for (int mt = 0; mt < 4; ++mt) {
            int r = wm * 64 + mt * 16 + r16;
            af[mt] = *(const short8*)(sA + (r * 4 + (q ^ ((r >> 1) & 3))) * 8);
        }
#pragma unroll
        for (int nt = 0; nt < 4; ++nt) {
            int r = wn * 64 + nt * 16 + r16;
            bf[nt] = *(const short8*)(sB + (r * 4 + (q ^ ((r >> 1) & 3))) * 8);
        }
#pragma unroll
        for (int mt = 0; mt < 4; ++mt)
#pragma unroll
            for (int nt = 0; nt < 4; ++nt)
                acc[mt][nt] = __builtin_amdgcn_mfma_f32_16x16x32_bf16(af[mt], bf[nt], acc[mt][nt], 0, 0, 0);
        __syncthreads();
    }

    if constexpr (MODE == 0) {
        ushort* ob = (ushort*)outb;
#pragma unroll
        for (int mt = 0; mt < 4; ++mt) {
            int row0 = m0 + wm * 64 + mt * 16 + q * 4;
#pragma unroll
            for (int nt = 0; nt < 4; ++nt) {
                int col = n0 + wn * 64 + nt * 16 + r16;
#pragma unroll
                for (int rg = 0; rg < 4; ++rg)
                    ob[(size_t)(row0 + rg) * N + col] = (ushort)f2bf(acc[mt][nt][rg]);
            }
        }
    } else {   // MODE 2
        ushort* ob = (ushort*)outb;
        int parity = r16 & 1;
#pragma unroll
        for (int mt = 0; mt < 4; ++mt) {
            int row0 = m0 + wm * 64 + mt * 16 + q * 4;
#pragma unroll
            for (int nt = 0; nt < 4; ++nt) {
                int ch = (n0 + wn * 64 + nt * 16 + r16) >> 1;
#pragma unroll
                for (int rg = 0; rg < 4; ++rg) {
                    float val = acc[mt][nt][rg];
                    float part = __shfl_xor(val, 1);
                    float uu = parity ? part : val;
                    float vv = parity ? val : part;
                    float g = uu * gelu_erf(vv);
                    if (!parity)
                        ob[(size_t)(row0 + rg) * 256 + ch] = (ushort)f2bf(g);
                }
            }
        }
    }
}

// ---------------------------------------------------------------- MFMA GEMM, N=128, 64-row tile
template<int K, bool RMS>
__global__ __launch_bounds__(256)
void gemm_n128_kernel(const __hip_bfloat16* __restrict__ Abf, const __hip_bfloat16* __restrict__ Wbf,
                      const float* __restrict__ bias,
                      const float* __restrict__ rsrc, float* __restrict__ rdst,
                      const float* __restrict__ scale,
                      const float* __restrict__ rms_s, const float* __restrict__ rms_b,
                      __hip_bfloat16* __restrict__ xn)
{
    constexpr int SMEM = RMS ? 39424 : 34816;
    __shared__ char smem[SMEM];
    short* sA = (short*)smem;                 // 64 rows x 32k = 4KB
    short* sB = sA + 2048;                    // 128 rows x 32k = 8KB
    float* sEp = (float*)smem;                // [128 ch][68 px] = 34816 (overlays staging)
    float* sPar = (float*)(smem + 34816);     // RMS: [64 px][17]
    float* sInv = (float*)(smem + 39168);     // RMS: [64 px]

    const short* A = (const short*)Abf;
    const short* W = (const short*)Wbf;

    int t = threadIdx.x;
    int lane = t & 63, wv = t >> 6;
    int m0 = blockIdx.x * 64;
    int q = lane >> 4, r16 = lane & 15;

    f32x4 acc[4][2];
#pragma unroll
    for (int nt = 0; nt < 2; ++nt) {
        float bv = bias[wv * 32 + nt * 16 + r16];
#pragma unroll
        for (int mt = 0; mt < 4; ++mt) acc[mt][nt] = (f32x4){bv, bv, bv, bv};
    }

    for (int kk = 0; kk < K; kk += 32) {
        {   // A: wave wv stages rows wv*16 .. +16
            int rbase = wv * 16;
            int row = rbase + (lane >> 2);
            int kc = (lane & 3) ^ ((row >> 1) & 3);
            const short* ga = A + (size_t)(m0 + row) * K + kk + kc * 8;
            __builtin_amdgcn_global_load_lds((const __attribute__((address_space(1))) void*)ga,
                                             (__attribute__((address_space(3))) void*)(sA + rbase * 32), 16, 0, 0);
        }
#pragma unroll
        for (int i = 0; i < 2; ++i) {   // B: wave wv stages channel rows wv*32 .. +32
            int rbase = wv * 32 + i * 16;
            int row = rbase + (lane >> 2);
            int kc = (lane & 3) ^ ((row >> 1) & 3);
            const short* gb = W + (size_t)row * K + kk + kc * 8;
            __builtin_amdgcn_global_load_lds((const __attribute__((address_space(1))) void*)gb,
                                             (__attribute__((address_space(3))) void*)(sB + rbase * 32), 16, 0, 0);
        }
        __syncthreads();

        short8 af[4], bf[2];
#pragma unroll
        for (int mt = 0; mt < 4; ++mt) {
            int r = mt * 16 + r16;
            af[mt] = *(const short8*)(sA + (r * 4 + (q ^ ((r >> 1) & 3))) * 8);
        }
#pragma unroll
        for (int nt = 0; nt < 2; ++nt) {
            int r = wv * 32 + nt * 16 + r16;
            bf[nt] = *(const short8*)(sB + (r * 4 + (q ^ ((r >> 1) & 3))) * 8);
        }
#pragma unroll
        for (int mt = 0; mt < 4; ++mt)
#pragma unroll
            for (int nt = 0; nt < 2; ++nt)
                acc[mt][nt] = __builtin_amdgcn_mfma_f32_16x16x32_bf16(af[mt], bf[nt], acc[mt][nt], 0, 0, 0);
        __syncthreads();
    }

    // single-pass epilogue: all 4 waves write their C fragments
#pragma unroll
    for (int mt = 0; mt < 4; ++mt)
#pragma unroll
        for (int nt = 0; nt < 2; ++nt) {
            int c = wv * 32 + nt * 16 + r16;
            int px = mt * 16 + q * 4;
#pragma unroll
            for (int rg = 0; rg < 4; ++rg)
                sEp[c * 68 + px + rg] = acc[mt][nt][rg];
        }
    __syncthreads();

    int c16 = t >> 4, l16 = t & 15;
    int p0 = m0 + l16 * 4;
    int b = p0 / HW, pp = p0 - b * HW;
    float sc = scale[0];
    f32x4 ov[8];
    f32x4 ps = (f32x4){0.f, 0.f, 0.f, 0.f};
#pragma unroll
    for (int i = 0; i < 8; ++i) {
        int c = c16 + i * 16;
        f32x4 v = *(const f32x4*)&sEp[c * 68 + l16 * 4];
        size_t gi = (size_t)(b * 128 + c) * HW + pp;
        f32x4 r = *(const f32x4*)&rsrc[gi];
        f32x4 o = r + sc * v;
        *(f32x4*)&rdst[gi] = o;
        if constexpr (RMS) {
            ov[i] = o;
#pragma unroll
            for (int rg = 0; rg < 4; ++rg) ps[rg] = fmaf(o[rg], o[rg], ps[rg]);
        }
    }
    if constexpr (RMS) {
#pragma unroll
        for (int rg = 0; rg < 4; ++rg) sPar[(l16 * 4 + rg) * 17 + c16] = ps[rg];
        __syncthreads();               // also fences sEp reads before sXn overlay
        if (t < 64) {
            float ssum = 0.f;
#pragma unroll
            for (int j = 0; j < 16; ++j) ssum += sPar[t * 17 + j];
            sInv[t] = 1.0f / sqrtf(ssum * 0.0078125f + 1e-6f);
        }
        __syncthreads();
        float iv[4];
#pragma unroll
        for (int rg = 0; rg < 4; ++rg) iv[rg] = sInv[l16 * 4 + rg];
        ushort* sXn = (ushort*)smem;   // overlay dead sEp: [64 px][132 ch-pad]
#pragma unroll
        for (int i = 0; i < 8; ++i) {
            int c = c16 + i * 16;
            float scs = rms_s[c], bcs = rms_b[c];
#pragma unroll
            for (int rg = 0; rg < 4; ++rg)
                sXn[(l16 * 4 + rg) * 132 + c] = (ushort)f2bf(fmaf(scs * ov[i][rg], iv[rg], bcs));
        }
        __syncthreads();
        {
            int px = t >> 2, qd = t & 3;
            const ushort* src = sXn + px * 132 + qd * 32;
            ushort* dst = (ushort*)xn + (size_t)(m0 + px) * 128 + qd * 32;
#pragma unroll
            for (int g = 0; g < 4; ++g)
                *(short8*)(dst + g * 8) = *(const short8*)(src + g * 8);
        }
    }
}

// ---------------------------------------------------------------- dwconv3x3 + gate, c4 x V4, hoisted weights
// 4 channels/thread, 4 vertical pixels/thread. Weights (9 taps x 4ch x u,v = 72 fp32)
// loaded ONCE into VGPRs; all 36 value loads branchless (clamp+mask) for max MLP.
// Rationale (r9 post-mortem): V=2 version is L1-BW-bound on per-tap weight re-loads
// (~1.5 KB/thread through L1 ~= 39 us); hoisting cuts L1 traffic ~1.8x.
__global__ __launch_bounds__(256, 3)
void dwgate_kernel(const __hip_bfloat16* __restrict__ t1, const float* __restrict__ dwt,
                   const float* __restrict__ dwb, __hip_bfloat16* __restrict__ tg)
{
    int t = threadIdx.x;
    int tc = t & 15;                   // 4-ch subchunk within 64-ch group
    int tp = t >> 4;                   // 0..15 pixel column
    int bx = blockIdx.x;
    int wseg = bx % 12; int tmp = bx / 12;
    int hq = tmp % 48; int b = tmp / 48;
    int cu = blockIdx.y * 64 + tc * 4; // u-channel base (0..252)
    int h0 = hq * 4;
    int w = wseg * 16 + tp;
    const ushort* t1u = (const ushort*)t1;

    f32x4 wu[9], wv[9];
#pragma unroll
    for (int tap = 0; tap < 9; ++tap) {
        wu[tap] = *(const f32x4*)(dwt + tap * 512 + cu);
        wv[tap] = *(const f32x4*)(dwt + tap * 512 + 256 + cu);
    }
    f32x4 bu = *(const f32x4*)(dwb + cu);
    f32x4 bv = *(const f32x4*)(dwb + 256 + cu);

    f32x4 au[4], av[4];
#pragma unroll
    for (int py = 0; py < 4; ++py) { au[py] = bu; av[py] = bv; }

#pragma unroll
    for (int r = 0; r < 6; ++r) {                    // source row h0-1+r
        int hh = h0 - 1 + r;
        bool okr = (unsigned)hh < 192u;
        int hhc = okr ? hh : 0;
#pragma unroll
        for (int dxi = 0; dxi < 3; ++dxi) {
            int w2 = w + dxi - 1;
            bool ok = okr && ((unsigned)w2 < 192u);
            int w2c = (w2 < 0) ? 0 : ((w2 > 191) ? 191 : w2);
            const ushort* p = t1u + (size_t)(b * HW + hhc * 192 + w2c) * 512 + cu;
            s16x4 u4 = *(const s16x4*)p;
            s16x4 v4 = *(const s16x4*)(p + 256);
            f32x4 uf, vf;
#pragma unroll
            for (int e = 0; e < 4; ++e) {
                uf[e] = ok ? bf2f((ushort)u4[e]) : 0.f;
                vf[e] = ok ? bf2f((ushort)v4[e]) : 0.f;
            }
#pragma unroll
            for (int py = 0; py < 4; ++py) {
                int dy = r - 1 - py;
                if (dy < -1 || dy > 1) continue;     // compile-time after unroll
                int tap = (dy + 1) * 3 + dxi;
#pragma unroll
                for (int e = 0; e < 4; ++e) {
                    au[py][e] = fmaf(wu[tap][e], uf[e], au[py][e]);
                    av[py][e] = fmaf(wv[tap][e], vf[e], av[py][e]);
                }
            }
        }
    }
#pragma unroll
    for (int py = 0; py < 4; ++py) {
        s16x4 o4;
#pragma unroll
        for (int e = 0; e < 4; ++e) o4[e] = (short)(ushort)f2bf(au[py][e] * gelu_erf(av[py][e]));
        int gp = b * HW + (h0 + py) * 192 + w;
        *(s16x4*)((ushort*)tg + (size_t)gp * 256 + cu) = o4;
    }
}

// ---------------------------------------------------------------- windowed attention (MFMA)
__device__ __forceinline__ int wpix(int wh, int ww, int m) {
    int ty = m >> 3, tx = m & 7;
    int hs = wh * 8 + ty + 4; if (hs >= 192) hs -= 192;
    int wsc = ww * 8 + tx + 4; if (wsc >= 192) wsc -= 192;
    return hs * 192 + wsc;
}
__device__ __forceinline__ int wreg(int wh, int ww, int m) {   // shift-mask region id
    int hr = wh * 8 + (m >> 3), wr = ww * 8 + (m & 7);
    return ((hr < 184) ? 0 : (hr < 188) ? 1 : 2) * 3 +
           ((wr < 184) ? 0 : (wr < 188) ? 1 : 2);
}

__global__ __launch_bounds__(256)
void attn_kernel(const __hip_bfloat16* __restrict__ qkv, const float* __restrict__ rpe,
                 __hip_bfloat16* __restrict__ attnout)
{
    __shared__ char smem[54288];
    int t = threadIdx.x;
    int lane = t & 63, head = t >> 6;
    int wh = blockIdx.x / 24, ww = blockIdx.x % 24;
    int b = blockIdx.y;
    int q = lane >> 4, r16 = lane & 15;

    float* rpe_s = (float*)(smem + 50688);
    for (int i = t; i < 900; i += 256) rpe_s[i] = rpe[i];

    char* Pbuf  = smem + head * 12672;
    char* VTbuf = Pbuf + 8448;
    const ushort* qkvu = (const ushort*)qkv;

    short8 aq[4], bk[4];
#pragma unroll
    for (int mt = 0; mt < 4; ++mt) {
        int pix = wpix(wh, ww, mt * 16 + r16);
        const ushort* rowp = qkvu + (size_t)(b * HW + pix) * 384 + head * 32 + q * 8;
        aq[mt] = *(const short8*)rowp;
        bk[mt] = *(const short8*)(rowp + 128);
    }
    {
        int pix = wpix(wh, ww, lane);
        const ushort* vp = qkvu + (size_t)(b * HW + pix) * 384 + 256 + head * 32;
        ushort* vt = (ushort*)VTbuf;           // VT[d][j]: row stride 66 ushorts
#pragma unroll
        for (int g = 0; g < 4; ++g) {
            short8 v8 = *(const short8*)(vp + g * 8);
#pragma unroll
            for (int e = 0; e < 8; ++e) vt[(g * 8 + e) * 66 + lane] = (ushort)v8[e];
        }
    }
    __syncthreads();

    f32x4 s[4][4];
#pragma unroll
    for (int mt = 0; mt < 4; ++mt)
#pragma unroll
        for (int nt = 0; nt < 4; ++nt) s[mt][nt] = (f32x4){0.f, 0.f, 0.f, 0.f};
#pragma unroll
    for (int mt = 0; mt < 4; ++mt)
#pragma unroll
        for (int nt = 0; nt < 4; ++nt)
            s[mt][nt] = __builtin_amdgcn_mfma_f32_16x16x32_bf16(aq[mt], bk[nt], s[mt][nt], 0, 0, 0);

    bool edge = (wh == 23) || (ww == 23);
    int tyj[4], txj[4], rgj[4];
#pragma unroll
    for (int nt = 0; nt < 4; ++nt) {
        int j = nt * 16 + r16;
        tyj[nt] = j >> 3; txj[nt] = j & 7;
        rgj[nt] = wreg(wh, ww, j);
    }
    float rinv[4][4];
#pragma unroll
    for (int mt = 0; mt < 4; ++mt) {
#pragma unroll
        for (int rg = 0; rg < 4; ++rg) {
            int i = mt * 16 + q * 4 + rg;
            int tyi = i >> 3, txi = i & 7;
            int rgi = edge ? wreg(wh, ww, i) : 0;
            float mx = -INFINITY;
#pragma unroll
            for (int nt = 0; nt < 4; ++nt) {
                float v = s[mt][nt][rg] * 0.17677669529663689f
                        + rpe_s[((tyi - tyj[nt] + 7) * 15 + (txi - txj[nt] + 7)) * 4 + head];
                if (edge && rgi != rgj[nt]) v = -INFINITY;
                s[mt][nt][rg] = v;
                mx = fmaxf(mx, v);
            }
            mx = fmaxf(mx, __shfl_xor(mx, 1));
            mx = fmaxf(mx, __shfl_xor(mx, 2));
            mx = fmaxf(mx, __shfl_xor(mx, 4));
            mx = fmaxf(mx, __shfl_xor(mx, 8));
            float sum = 0.f;
#pragma unroll
            for (int nt = 0; nt < 4; ++nt) {
                float e = __expf(s[mt][nt][rg] - mx);
                s[mt][nt][rg] = e;
                sum += e;
            }
            sum += __shfl_xor(sum, 1);
            sum += __shfl_xor(sum, 2);
            sum += __shfl_xor(sum, 4);
            sum += __shfl_xor(sum, 8);
            rinv[mt][rg] = 1.0f / sum;
        }
    }

    ushort* Pu = (ushort*)Pbuf;                 // row stride 66 ushorts
#pragma unroll
    for (int mt = 0; mt < 4; ++mt)
#pragma unroll
        for (int rg = 0; rg < 4; ++rg) {
            int i = mt * 16 + q * 4 + rg;
#pragma unroll
            for (int nt = 0; nt < 4; ++nt)
                Pu[i * 66 + nt * 16 + r16] = (ushort)f2bf(s[mt][nt][rg]);
        }
    __syncthreads();   // fence: P ushort-writes before uint-reads (TBAA)

    f32x4 o[4][2];
#pragma unroll
    for (int mt = 0; mt < 4; ++mt) { o[mt][0] = (f32x4){0,0,0,0}; o[mt][1] = (f32x4){0,0,0,0}; }
    const uint* Pw = (const uint*)Pbuf;         // dword units, row stride 33
    const uint* Vw = (const uint*)VTbuf;
#pragma unroll
    for (int ks = 0; ks < 2; ++ks) {
        short8 ap[4];
#pragma unroll
        for (int mt = 0; mt < 4; ++mt) {
            int base = (mt * 16 + r16) * 33 + ks * 16 + q * 4;
            uint d0 = Pw[base], d1 = Pw[base + 1], d2 = Pw[base + 2], d3 = Pw[base + 3];
            union { uint u[4]; short8 s8; } cv; cv.u[0] = d0; cv.u[1] = d1; cv.u[2] = d2; cv.u[3] = d3;
            ap[mt] = cv.s8;
        }
        short8 bv[2];
#pragma unroll
        for (int nt = 0; nt < 2; ++nt) {
            int base = (nt * 16 + r16) * 33 + ks * 16 + q * 4;
            uint d0 = Vw[base], d1 = Vw[base + 1], d2 = Vw[base + 2], d3 = Vw[base + 3];
            union { uint u[4]; short8 s8; } cv; cv.u[0] = d0; cv.u[1] = d1; cv.u[2] = d2; cv.u[3] = d3;
            bv[nt] = cv.s8;
        }
#pragma unroll
        for (int mt = 0; mt < 4; ++mt)
#pragma unroll
            for (int nt = 0; nt < 2; ++nt)
                o[mt][nt] = __builtin_amdgcn_mfma_f32_16x16x32_bf16(ap[mt], bv[nt], o[mt][nt], 0, 0, 0);
    }
    __syncthreads();   // fence: P uint-reads complete before Of float-overwrite (TBAA WAR)

    float* Of = (float*)Pbuf;                   // row stride 33 dwords
#pragma unroll
    for (int mt = 0; mt < 4; ++mt)
#pragma unroll
        for (int rg = 0; rg < 4; ++rg) {
            int i = mt * 16 + q * 4 + rg;
            float sc = rinv[mt][rg];
            Of[i * 33 + r16]      = o[mt][0][rg] * sc;
            Of[i * 33 + 16 + r16] = o[mt][1][rg] * sc;
        }
    __syncthreads();   // fence: Of writes before cross-lane reads
    {
        int pix = wpix(wh, ww, lane);
        ushort* ob = (ushort*)attnout + (size_t)(b * HW + pix) * 128 + head * 32;
#pragma unroll
        for (int g = 0; g < 4; ++g) {
            short8 o8;
#pragma unroll
            for (int e = 0; e < 8; ++e) o8[e] = (short)(ushort)f2bf(Of[lane * 33 + g * 8 + e]);
            *(short8*)(ob + g * 8) = o8;
        }
    }
}

// ---------------------------------------------------------------- launch
extern "C" void kernel_launch(void* const* d_in, const int* in_sizes, int n_in,
                              void* d_out, int out_size, void* d_ws, size_t ws_size,
                              hipStream_t stream)
{
    const float* x     = (const float*)d_in[0];
    const float* cg_s  = (const float*)d_in[1];
    const float* cg_b  = (const float*)d_in[2];
    const float* pw1_w = (const float*)d_in[3];
    const float* pw1_b = (const float*)d_in[4];
    const float* dw_w  = (const float*)d_in[5];
    const float* dw_b  = (const float*)d_in[6];
    const float* pw2_w = (const float*)d_in[7];
    const float* pw2_b = (const float*)d_in[8];
    const float* beta  = (const float*)d_in[9];
    const float* at_s  = (const float*)d_in[10];
    const float* at_b  = (const float*)d_in[11];
    const float* qkv_w = (const float*)d_in[12];
    const float* qkv_b = (const float*)d_in[13];
    const float* rpe   = (const float*)d_in[14];
    const float* proj_w= (const float*)d_in[15];
    const float* proj_b= (const float*)d_in[16];
    const float* alpha = (const float*)d_in[17];
    const float* ff_s  = (const float*)d_in[18];
    const float* ff_b  = (const float*)d_in[19];
    const float* fc1_w = (const float*)d_in[20];
    const float* fc1_b = (const float*)d_in[21];
    const float* fc2_w = (const float*)d_in[22];
    const float* fc2_b = (const float*)d_in[23];
    const float* gamma = (const float*)d_in[24];
    float* out = (float*)d_out;

    char* ws = (char*)d_ws;
    __hip_bfloat16* Xn    = (__hip_bfloat16*)ws;
    __hip_bfloat16* t1    = (__hip_bfloat16*)(ws + 18874368);
    __hip_bfloat16* qkvb  = t1;
    __hip_bfloat16* tg    = (__hip_bfloat16*)(ws + 94371840);
    __hip_bfloat16* attno = tg;
    char* wsw = ws + 132120576;
    ushort* w1b  = (ushort*)(wsw);             // 512*128
    ushort* w2b  = (ushort*)(wsw + 131072);    // 128*256
    ushort* wqb  = (ushort*)(wsw + 196608);    // 384*128
    ushort* wpb  = (ushort*)(wsw + 294912);    // 128*128
    ushort* wf1b = (ushort*)(wsw + 327680);    // 512*128 (paired u/v)
    ushort* wf2b = (ushort*)(wsw + 458752);    // 128*256
    float*  dwt  = (float*) (wsw + 524288);    // 9*512 fp32
    float*  bg1  = (float*) (wsw + 542720);    // 512 fp32 (paired fc1 bias)

    wconv_kernel<<<1044, 256, 0, stream>>>(pw1_w, pw2_w, qkv_w, proj_w, fc1_w, fc2_w, dw_w, fc1_b,
                                           w1b, w2b, wqb, wpb, wf1b, wf2b, dwt, bg1);

    // ---- stage 1: conv_gated_block (pw2 fuses residual + at-RMSNorm)
    rmsnorm_t_kernel<<<288, 256, 0, stream>>>(x, cg_s, cg_b, Xn);
    gemm_kernel<128, 0><<<dim3(576, 4), 256, 0, stream>>>(Xn, (__hip_bfloat16*)w1b, pw1_b, 512, t1);
    dwgate_kernel<<<dim3(1152, 4), 256, 0, stream>>>(t1, dwt, dw_b, tg);
    gemm_n128_kernel<256, true><<<1152, 256, 0, stream>>>(tg, (__hip_bfloat16*)w2b, pw2_b,
                                                          x, out, beta, at_s, at_b, Xn);

    // ---- stage 2: window attention (proj fuses residual + ff-RMSNorm)
    gemm_kernel<128, 0><<<dim3(576, 3), 256, 0, stream>>>(Xn, (__hip_bfloat16*)wqb, qkv_b, 384, qkvb);
    attn_kernel<<<dim3(576, 2), 256, 0, stream>>>(qkvb, rpe, attno);
    gemm_n128_kernel<128, true><<<1152, 256, 0, stream>>>(attno, (__hip_bfloat16*)wpb, proj_b,
                                                          out, out, alpha, ff_s, ff_b, Xn);

    // ---- stage 3: gated FFN (gate fused into fc1 GEMM epilogue)
    gemm_kernel<128, 2><<<dim3(576, 4), 256, 0, stream>>>(Xn, (__hip_bfloat16*)wf1b, bg1, 512, tg);
    gemm_n128_kernel<256, false><<<1152, 256, 0, stream>>>(tg, (__hip_bfloat16*)wf2b, fc2_b,
                                                           out, out, gamma, nullptr, nullptr, nullptr);
}

// Round 11
// 378.665 us; speedup vs baseline: 1.2223x; 1.0458x over previous
//
#include <hip/hip_runtime.h>
#include <hip/hip_bf16.h>
#include <math.h>

#define HW   36864        // 192*192
#define BHW  73728        // 2*HW

typedef float f32x4 __attribute__((ext_vector_type(4)));
typedef short short8 __attribute__((ext_vector_type(8)));
typedef short s16x4 __attribute__((ext_vector_type(4)));   // NB: 'short4' is a HIP built-in type

__device__ __forceinline__ unsigned f2bf(float f) {        // fp32 -> bf16 bits, RNE
    unsigned u = __float_as_uint(f);
    return (u + 0x7fffu + ((u >> 16) & 1u)) >> 16;
}
__device__ __forceinline__ float bf2f(unsigned short s) {  // bf16 bits -> fp32
    return __uint_as_float(((unsigned)s) << 16);
}
__device__ __forceinline__ float gelu_erf(float v) {
    return v * 0.5f * (1.0f + erff(v * 0.70710678118654752f));
}
// tanh-approx gelu as x*sigmoid(2*0.7978845608*(x+0.044715x^3)); <1e-3 abs dev from erf-gelu.
// v_exp + v_rcp (~7 instr) vs erff (~25) — dwgate/fc1-gate are VALU-heavy (r10 post-mortem).
__device__ __forceinline__ float gelu_fast(float x) {
    float y = 1.5957691216057308f * fmaf(0.044715f * x * x, x, x);
    return x / (1.0f + __expf(-y));
}

// ---------------------------------------------------------------- weight prep
// fc1 weights/bias PAIRED: col 2c = u-channel c, col 2c+1 = v-channel c (fused gate epilogue).
__global__ __launch_bounds__(256)
void wconv_kernel(const float* __restrict__ w1, const float* __restrict__ w2,
                  const float* __restrict__ wq, const float* __restrict__ wp,
                  const float* __restrict__ wf1, const float* __restrict__ wf2,
                  const float* __restrict__ dww, const float* __restrict__ fb1,
                  ushort* __restrict__ o1, ushort* __restrict__ o2, ushort* __restrict__ oq,
                  ushort* __restrict__ op, ushort* __restrict__ of1, ushort* __restrict__ of2,
                  float* __restrict__ dwt, float* __restrict__ bg)
{
    int i = blockIdx.x * 256 + threadIdx.x;
    if      (i <  65536) o1 [i         ] = (ushort)f2bf(w1 [i         ]);
    else if (i <  98304) o2 [i -  65536] = (ushort)f2bf(w2 [i -  65536]);
    else if (i < 147456) oq [i -  98304] = (ushort)f2bf(wq [i -  98304]);
    else if (i < 163840) op [i - 147456] = (ushort)f2bf(wp [i - 147456]);
    else if (i < 229376) {
        int j = i - 163840;            // paired fc1: col=j>>7, k=j&127
        int col = j >> 7, k = j & 127;
        of1[j] = (ushort)f2bf(wf1[((size_t)((col & 1) * 256 + (col >> 1))) * 128 + k]);
    }
    else if (i < 262144) of2[i - 229376] = (ushort)f2bf(wf2[i - 229376]);
    else if (i < 266752) {
        int j = i - 262144;            // j = tap*512 + c
        int tap = j >> 9, c = j & 511;
        dwt[j] = dww[c * 9 + tap];
    }
    else if (i < 267264) {
        int j = i - 266752;            // paired fc1 bias
        bg[j] = fb1[(j & 1) * 256 + (j >> 1)];
    }
}

// ---------------------------------------------------------------- rmsnorm (NCHW fp32 -> pixel-major bf16)
__global__ __launch_bounds__(256)
void rmsnorm_t_kernel(const float* __restrict__ src, const float* __restrict__ s,
                      const float* __restrict__ bi, __hip_bfloat16* __restrict__ dst)
{
    int P = blockIdx.x * 256 + threadIdx.x;          // pixel id in [0, BHW)
    int b = P / HW, pp = P - b * HW;
    const float* xb = src + (size_t)b * 128 * HW + pp;
    float ss = 0.f;
#pragma unroll 8
    for (int c = 0; c < 128; ++c) { float v = xb[(size_t)c * HW]; ss = fmaf(v, v, ss); }
    float inv = 1.0f / sqrtf(ss * 0.0078125f + 1e-6f);
    unsigned* drow = (unsigned*)(dst + (size_t)P * 128);
#pragma unroll 4
    for (int c = 0; c < 128; c += 2) {
        float v0 = fmaf(s[c]     * xb[(size_t)c * HW],       inv, bi[c]);
        float v1 = fmaf(s[c + 1] * xb[(size_t)(c + 1) * HW], inv, bi[c + 1]);
        drow[c >> 1] = f2bf(v0) | (f2bf(v1) << 16);
    }
}

// ---------------------------------------------------------------- MFMA GEMM (128x128 tile)
// MODE 0: store bf16 pixel-major (BHW,N), direct scalar stores.
// MODE 2: N==512 paired u/v cols; store u*gelu(v) bf16 (BHW,256) via shfl pairing.
template<int K, int MODE>
__global__ __launch_bounds__(256)
void gemm_kernel(const __hip_bfloat16* __restrict__ Abf, const __hip_bfloat16* __restrict__ Wbf,
                 const float* __restrict__ bias, int N,
                 __hip_bfloat16* __restrict__ outb)
{
    __shared__ char smem[16384];
    short* sA = (short*)smem;
    short* sB = sA + 4096;

    const short* A = (const short*)Abf;
    const short* W = (const short*)Wbf;

    int t = threadIdx.x;
    int lane = t & 63, wv = t >> 6;
    int wm = wv & 1, wn = wv >> 1;
    int m0 = blockIdx.x * 128;
    int n0 = blockIdx.y * 128;
    int q = lane >> 4, r16 = lane & 15;

    f32x4 acc[4][4];
#pragma unroll
    for (int nt = 0; nt < 4; ++nt) {
        float bv = bias[n0 + wn * 64 + nt * 16 + r16];
#pragma unroll
        for (int mt = 0; mt < 4; ++mt) acc[mt][nt] = (f32x4){bv, bv, bv, bv};
    }

    for (int kk = 0; kk < K; kk += 32) {
#pragma unroll
        for (int i = 0; i < 2; ++i) {
            int rbase = wv * 32 + i * 16;
            int row = rbase + (lane >> 2);
            int kc = (lane & 3) ^ ((row >> 1) & 3);
            const short* ga = A + (size_t)(m0 + row) * K + kk + kc * 8;
            const short* gb = W + (size_t)(n0 + row) * K + kk + kc * 8;
            __builtin_amdgcn_global_load_lds((const __attribute__((address_space(1))) void*)ga,
                                             (__attribute__((address_space(3))) void*)(sA + rbase * 32), 16, 0, 0);
            __builtin_amdgcn_global_load_lds((const __attribute__((address_space(1))) void*)gb,
                                             (__attribute__((address_space(3))) void*)(sB + rbase * 32), 16, 0, 0);
        }
        __syncthreads();

        short8 af[4], bf[4];
#pragma unroll
        for (int mt = 0; mt < 4; ++mt) {
            int r = wm * 64 + mt * 16 + r16;
            af[mt] = *(const short8*)(sA + (r * 4 + (q ^ ((r >> 1) & 3))) * 8);
        }
#pragma unroll
        for (int nt = 0; nt < 4; ++nt) {
            int r = wn * 64 + nt * 16 + r16;
            bf[nt] = *(const short8*)(sB + (r * 4 + (q ^ ((r >> 1) & 3))) * 8);
        }
#pragma unroll
        for (int mt = 0; mt < 4; ++mt)
#pragma unroll
            for (int nt = 0; nt < 4; ++nt)
                acc[mt][nt] = __builtin_amdgcn_mfma_f32_16x16x32_bf16(af[mt], bf[nt], acc[mt][nt], 0, 0, 0);
        __syncthreads();
    }

    if constexpr (MODE == 0) {
        ushort* ob = (ushort*)outb;
#pragma unroll
        for (int mt = 0; mt < 4; ++mt) {
            int row0 = m0 + wm * 64 + mt * 16 + q * 4;
#pragma unroll
            for (int nt = 0; nt < 4; ++nt) {
                int col = n0 + wn * 64 + nt * 16 + r16;
#pragma unroll
                for (int rg = 0; rg < 4; ++rg)
                    ob[(size_t)(row0 + rg) * N + col] = (ushort)f2bf(acc[mt][nt][rg]);
            }
        }
    } else {   // MODE 2
        ushort* ob = (ushort*)outb;
        int parity = r16 & 1;
#pragma unroll
        for (int mt = 0; mt < 4; ++mt) {
            int row0 = m0 + wm * 64 + mt * 16 + q * 4;
#pragma unroll
            for (int nt = 0; nt < 4; ++nt) {
                int ch = (n0 + wn * 64 + nt * 16 + r16) >> 1;
#pragma unroll
                for (int rg = 0; rg < 4; ++rg) {
                    float val = acc[mt][nt][rg];
                    float part = __shfl_xor(val, 1);
                    float uu = parity ? part : val;
                    float vv = parity ? val : part;
                    float g = uu * gelu_fast(vv);
                    if (!parity)
                        ob[(size_t)(row0 + rg) * 256 + ch] = (ushort)f2bf(g);
                }
            }
        }
    }
}

// ---------------------------------------------------------------- MFMA GEMM, N=128, 64-row tile
template<int K, bool RMS>
__global__ __launch_bounds__(256)
void gemm_n128_kernel(const __hip_bfloat16* __restrict__ Abf, const __hip_bfloat16* __restrict__ Wbf,
                      const float* __restrict__ bias,
                      const float* __restrict__ rsrc, float* __restrict__ rdst,
                      const float* __restrict__ scale,
                      const float* __restrict__ rms_s, const float* __restrict__ rms_b,
                      __hip_bfloat16* __restrict__ xn)
{
    constexpr int SMEM = RMS ? 39424 : 34816;
    __shared__ char smem[SMEM];
    short* sA = (short*)smem;                 // 64 rows x 32k = 4KB
    short* sB = sA + 2048;                    // 128 rows x 32k = 8KB
    float* sEp = (float*)smem;                // [128 ch][68 px] = 34816 (overlays staging)
    float* sPar = (float*)(smem + 34816);     // RMS: [64 px][17]
    float* sInv = (float*)(smem + 39168);     // RMS: [64 px]

    const short* A = (const short*)Abf;
    const short* W = (const short*)Wbf;

    int t = threadIdx.x;
    int lane = t & 63, wv = t >> 6;
    int m0 = blockIdx.x * 64;
    int q = lane >> 4, r16 = lane & 15;

    f32x4 acc[4][2];
#pragma unroll
    for (int nt = 0; nt < 2; ++nt) {
        float bv = bias[wv * 32 + nt * 16 + r16];
#pragma unroll
        for (int mt = 0; mt < 4; ++mt) acc[mt][nt] = (f32x4){bv, bv, bv, bv};
    }

    for (int kk = 0; kk < K; kk += 32) {
        {   // A: wave wv stages rows wv*16 .. +16
            int rbase = wv * 16;
            int row = rbase + (lane >> 2);
            int kc = (lane & 3) ^ ((row >> 1) & 3);
            const short* ga = A + (size_t)(m0 + row) * K + kk + kc * 8;
            __builtin_amdgcn_global_load_lds((const __attribute__((address_space(1))) void*)ga,
                                             (__attribute__((address_space(3))) void*)(sA + rbase * 32), 16, 0, 0);
        }
#pragma unroll
        for (int i = 0; i < 2; ++i) {   // B: wave wv stages channel rows wv*32 .. +32
            int rbase = wv * 32 + i * 16;
            int row = rbase + (lane >> 2);
            int kc = (lane & 3) ^ ((row >> 1) & 3);
            const short* gb = W + (size_t)row * K + kk + kc * 8;
            __builtin_amdgcn_global_load_lds((const __attribute__((address_space(1))) void*)gb,
                                             (__attribute__((address_space(3))) void*)(sB + rbase * 32), 16, 0, 0);
        }
        __syncthreads();

        short8 af[4], bf[2];
#pragma unroll
        for (int mt = 0; mt < 4; ++mt) {
            int r = mt * 16 + r16;
            af[mt] = *(const short8*)(sA + (r * 4 + (q ^ ((r >> 1) & 3))) * 8);
        }
#pragma unroll
        for (int nt = 0; nt < 2; ++nt) {
            int r = wv * 32 + nt * 16 + r16;
            bf[nt] = *(const short8*)(sB + (r * 4 + (q ^ ((r >> 1) & 3))) * 8);
        }
#pragma unroll
        for (int mt = 0; mt < 4; ++mt)
#pragma unroll
            for (int nt = 0; nt < 2; ++nt)
                acc[mt][nt] = __builtin_amdgcn_mfma_f32_16x16x32_bf16(af[mt], bf[nt], acc[mt][nt], 0, 0, 0);
        __syncthreads();
    }

    // single-pass epilogue: all 4 waves write their C fragments
#pragma unroll
    for (int mt = 0; mt < 4; ++mt)
#pragma unroll
        for (int nt = 0; nt < 2; ++nt) {
            int c = wv * 32 + nt * 16 + r16;
            int px = mt * 16 + q * 4;
#pragma unroll
            for (int rg = 0; rg < 4; ++rg)
                sEp[c * 68 + px + rg] = acc[mt][nt][rg];
        }
    __syncthreads();

    int c16 = t >> 4, l16 = t & 15;
    int p0 = m0 + l16 * 4;
    int b = p0 / HW, pp = p0 - b * HW;
    float sc = scale[0];
    f32x4 ov[8];
    f32x4 ps = (f32x4){0.f, 0.f, 0.f, 0.f};
#pragma unroll
    for (int i = 0; i < 8; ++i) {
        int c = c16 + i * 16;
        f32x4 v = *(const f32x4*)&sEp[c * 68 + l16 * 4];
        size_t gi = (size_t)(b * 128 + c) * HW + pp;
        f32x4 r = *(const f32x4*)&rsrc[gi];
        f32x4 o = r + sc * v;
        *(f32x4*)&rdst[gi] = o;
        if constexpr (RMS) {
            ov[i] = o;
#pragma unroll
            for (int rg = 0; rg < 4; ++rg) ps[rg] = fmaf(o[rg], o[rg], ps[rg]);
        }
    }
    if constexpr (RMS) {
#pragma unroll
        for (int rg = 0; rg < 4; ++rg) sPar[(l16 * 4 + rg) * 17 + c16] = ps[rg];
        __syncthreads();               // also fences sEp reads before sXn overlay
        if (t < 64) {
            float ssum = 0.f;
#pragma unroll
            for (int j = 0; j < 16; ++j) ssum += sPar[t * 17 + j];
            sInv[t] = 1.0f / sqrtf(ssum * 0.0078125f + 1e-6f);
        }
        __syncthreads();
        float iv[4];
#pragma unroll
        for (int rg = 0; rg < 4; ++rg) iv[rg] = sInv[l16 * 4 + rg];
        ushort* sXn = (ushort*)smem;   // overlay dead sEp: [64 px][132 ch-pad]
#pragma unroll
        for (int i = 0; i < 8; ++i) {
            int c = c16 + i * 16;
            float scs = rms_s[c], bcs = rms_b[c];
#pragma unroll
            for (int rg = 0; rg < 4; ++rg)
                sXn[(l16 * 4 + rg) * 132 + c] = (ushort)f2bf(fmaf(scs * ov[i][rg], iv[rg], bcs));
        }
        __syncthreads();
        {
            int px = t >> 2, qd = t & 3;
            const ushort* src = sXn + px * 132 + qd * 32;
            ushort* dst = (ushort*)xn + (size_t)(m0 + px) * 128 + qd * 32;
#pragma unroll
            for (int g = 0; g < 4; ++g)
                *(short8*)(dst + g * 8) = *(const short8*)(src + g * 8);
        }
    }
}

// ---------------------------------------------------------------- dwconv3x3 + gate, full-row v5
// 4x4 pixel tile; tc=t&63 spans ALL 256 gate channels (4 ch/thread), tp=t>>6 = pixel column.
// Every wave-level load/store is a full contiguous 512B pixel row: no partial-sector
// write amplification (r10: WRITE_SIZE 100MB for 37.7MB of data), full-row reads.
// Weights (9 taps x 4ch x u,v = 72 fp32) hoisted once; bounds via clamp+mask; fast gelu.
__global__ __launch_bounds__(256, 3)
void dwgate_kernel(const __hip_bfloat16* __restrict__ t1, const float* __restrict__ dwt,
                   const float* __restrict__ dwb, __hip_bfloat16* __restrict__ tg)
{
    int t = threadIdx.x;
    int tc = t & 63;                   // channel chunk (4 ch) over all 256
    int tp = t >> 6;                   // 0..3 pixel column
    int bx = blockIdx.x;               // 4608 = 2 * 48 * 48
    int b = bx / 2304; int tt = bx % 2304;
    int th = tt / 48, tw = tt % 48;
    int h0 = th * 4, w = tw * 4 + tp;
    int cu = tc * 4;                   // u-channel base 0..252
    const ushort* t1u = (const ushort*)t1;

    f32x4 wu[9], wv[9];
#pragma unroll
    for (int tap = 0; tap < 9; ++tap) {
        wu[tap] = *(const f32x4*)(dwt + tap * 512 + cu);
        wv[tap] = *(const f32x4*)(dwt + tap * 512 + 256 + cu);
    }
    f32x4 bu = *(const f32x4*)(dwb + cu);
    f32x4 bv = *(const f32x4*)(dwb + 256 + cu);

    f32x4 au[4], av[4];
#pragma unroll
    for (int py = 0; py < 4; ++py) { au[py] = bu; av[py] = bv; }

#pragma unroll
    for (int r = 0; r < 6; ++r) {                    // source row h0-1+r
        int hh = h0 - 1 + r;
        bool okr = (unsigned)hh < 192u;
        int hhc = okr ? hh : 0;
#pragma unroll
        for (int dxi = 0; dxi < 3; ++dxi) {
            int w2 = w + dxi - 1;
            bool ok = okr && ((unsigned)w2 < 192u);
            int w2c = (w2 < 0) ? 0 : ((w2 > 191) ? 191 : w2);
            const ushort* p = t1u + (size_t)(b * HW + hhc * 192 + w2c) * 512 + cu;
            s16x4 u4 = *(const s16x4*)p;
            s16x4 v4 = *(const s16x4*)(p + 256);
            f32x4 uf, vf;
#pragma unroll
            for (int e = 0; e < 4; ++e) {
                uf[e] = ok ? bf2f((ushort)u4[e]) : 0.f;
                vf[e] = ok ? bf2f((ushort)v4[e]) : 0.f;
            }
#pragma unroll
            for (int py = 0; py < 4; ++py) {
                int dy = r - 1 - py;
                if (dy < -1 || dy > 1) continue;     // compile-time after unroll
                int tap = (dy + 1) * 3 + dxi;
#pragma unroll
                for (int e = 0; e < 4; ++e) {
                    au[py][e] = fmaf(wu[tap][e], uf[e], au[py][e]);
                    av[py][e] = fmaf(wv[tap][e], vf[e], av[py][e]);
                }
            }
        }
    }
#pragma unroll
    for (int py = 0; py < 4; ++py) {
        s16x4 o4;
#pragma unroll
        for (int e = 0; e < 4; ++e) o4[e] = (short)(ushort)f2bf(au[py][e] * gelu_fast(av[py][e]));
        int gp = b * HW + (h0 + py) * 192 + w;
        *(s16x4*)((ushort*)tg + (size_t)gp * 256 + cu) = o4;
    }
}

// ---------------------------------------------------------------- windowed attention (MFMA)
__device__ __forceinline__ int wpix(int wh, int ww, int m) {
    int ty = m >> 3, tx = m & 7;
    int hs = wh * 8 + ty + 4; if (hs >= 192) hs -= 192;
    int wsc = ww * 8 + tx + 4; if (wsc >= 192) wsc -= 192;
    return hs * 192 + wsc;
}
__device__ __forceinline__ int wreg(int wh, int ww, int m) {   // shift-mask region id
    int hr = wh * 8 + (m >> 3), wr = ww * 8 + (m & 7);
    return ((hr < 184) ? 0 : (hr < 188) ? 1 : 2) * 3 +
           ((wr < 184) ? 0 : (wr < 188) ? 1 : 2);
}

__global__ __launch_bounds__(256)
void attn_kernel(const __hip_bfloat16* __restrict__ qkv, const float* __restrict__ rpe,
                 __hip_bfloat16* __restrict__ attnout)
{
    __shared__ char smem[54288];
    int t = threadIdx.x;
    int lane = t & 63, head = t >> 6;
    int wh = blockIdx.x / 24, ww = blockIdx.x % 24;
    int b = blockIdx.y;
    int q = lane >> 4, r16 = lane & 15;

    float* rpe_s = (float*)(smem + 50688);
    for (int i = t; i < 900; i += 256) rpe_s[i] = rpe[i];

    char* Pbuf  = smem + head * 12672;
    char* VTbuf = Pbuf + 8448;
    const ushort* qkvu = (const ushort*)qkv;

    short8 aq[4], bk[4];
#pragma unroll
    for (int mt = 0; mt < 4; ++mt) {
        int pix = wpix(wh, ww, mt * 16 + r16);
        const ushort* rowp = qkvu + (size_t)(b * HW + pix) * 384 + head * 32 + q * 8;
        aq[mt] = *(const short8*)rowp;
        bk[mt] = *(const short8*)(rowp + 128);
    }
    {
        int pix = wpix(wh, ww, lane);
        const ushort* vp = qkvu + (size_t)(b * HW + pix) * 384 + 256 + head * 32;
        ushort* vt = (ushort*)VTbuf;           // VT[d][j]: row stride 66 ushorts
#pragma unroll
        for (int g = 0; g < 4; ++g) {
            short8 v8 = *(const short8*)(vp + g * 8);
#pragma unroll
            for (int e = 0; e < 8; ++e) vt[(g * 8 + e) * 66 + lane] = (ushort)v8[e];
        }
    }
    __syncthreads();

    f32x4 s[4][4];
#pragma unroll
    for (int mt = 0; mt < 4; ++mt)
#pragma unroll
        for (int nt = 0; nt < 4; ++nt) s[mt][nt] = (f32x4){0.f, 0.f, 0.f, 0.f};
#pragma unroll
    for (int mt = 0; mt < 4; ++mt)
#pragma unroll
        for (int nt = 0; nt < 4; ++nt)
            s[mt][nt] = __builtin_amdgcn_mfma_f32_16x16x32_bf16(aq[mt], bk[nt], s[mt][nt], 0, 0, 0);

    bool edge = (wh == 23) || (ww == 23);
    int tyj[4], txj[4], rgj[4];
#pragma unroll
    for (int nt = 0; nt < 4; ++nt) {
        int j = nt * 16 + r16;
        tyj[nt] = j >> 3; txj[nt] = j & 7;
        rgj[nt] = wreg(wh, ww, j);
    }
    float rinv[4][4];
#pragma unroll
    for (int mt = 0; mt < 4; ++mt) {
#pragma unroll
        for (int rg = 0; rg < 4; ++rg) {
            int i = mt * 16 + q * 4 + rg;
            int tyi = i >> 3, txi = i & 7;
            int rgi = edge ? wreg(wh, ww, i) : 0;
            float mx = -INFINITY;
#pragma unroll
            for (int nt = 0; nt < 4; ++nt) {
                float v = s[mt][nt][rg] * 0.17677669529663689f
                        + rpe_s[((tyi - tyj[nt] + 7) * 15 + (txi - txj[nt] + 7)) * 4 + head];
                if (edge && rgi != rgj[nt]) v = -INFINITY;
                s[mt][nt][rg] = v;
                mx = fmaxf(mx, v);
            }
            mx = fmaxf(mx, __shfl_xor(mx, 1));
            mx = fmaxf(mx, __shfl_xor(mx, 2));
            mx = fmaxf(mx, __shfl_xor(mx, 4));
            mx = fmaxf(mx, __shfl_xor(mx, 8));
            float sum = 0.f;
#pragma unroll
            for (int nt = 0; nt < 4; ++nt) {
                float e = __expf(s[mt][nt][rg] - mx);
                s[mt][nt][rg] = e;
                sum += e;
            }
            sum += __shfl_xor(sum, 1);
            sum += __shfl_xor(sum, 2);
            sum += __shfl_xor(sum, 4);
            sum += __shfl_xor(sum, 8);
            rinv[mt][rg] = 1.0f / sum;
        }
    }

    ushort* Pu = (ushort*)Pbuf;                 // row stride 66 ushorts
#pragma unroll
    for (int mt = 0; mt < 4; ++mt)
#pragma unroll
        for (int rg = 0; rg < 4; ++rg) {
            int i = mt * 16 + q * 4 + rg;
#pragma unroll
            for (int nt = 0; nt < 4; ++nt)
                Pu[i * 66 + nt * 16 + r16] = (ushort)f2bf(s[mt][nt][rg]);
        }
    __syncthreads();   // fence: P ushort-writes before uint-reads (TBAA)

    f32x4 o[4][2];
#pragma unroll
    for (int mt = 0; mt < 4; ++mt) { o[mt][0] = (f32x4){0,0,0,0}; o[mt][1] = (f32x4){0,0,0,0}; }
    const uint* Pw = (const uint*)Pbuf;         // dword units, row stride 33
    const uint* Vw = (const uint*)VTbuf;
#pragma unroll
    for (int ks = 0; ks < 2; ++ks) {
        short8 ap[4];
#pragma unroll
        for (int mt = 0; mt < 4; ++mt) {
            int base = (mt * 16 + r16) * 33 + ks * 16 + q * 4;
            uint d0 = Pw[base], d1 = Pw[base + 1], d2 = Pw[base + 2], d3 = Pw[base + 3];
            union { uint u[4]; short8 s8; } cv; cv.u[0] = d0; cv.u[1] = d1; cv.u[2] = d2; cv.u[3] = d3;
            ap[mt] = cv.s8;
        }
        short8 bv[2];
#pragma unroll
        for (int nt = 0; nt < 2; ++nt) {
            int base = (nt * 16 + r16) * 33 + ks * 16 + q * 4;
            uint d0 = Vw[base], d1 = Vw[base + 1], d2 = Vw[base + 2], d3 = Vw[base + 3];
            union { uint u[4]; short8 s8; } cv; cv.u[0] = d0; cv.u[1] = d1; cv.u[2] = d2; cv.u[3] = d3;
            bv[nt] = cv.s8;
        }
#pragma unroll
        for (int mt = 0; mt < 4; ++mt)
#pragma unroll
            for (int nt = 0; nt < 2; ++nt)
                o[mt][nt] = __builtin_amdgcn_mfma_f32_16x16x32_bf16(ap[mt], bv[nt], o[mt][nt], 0, 0, 0);
    }
    __syncthreads();   // fence: P uint-reads complete before Of float-overwrite (TBAA WAR)

    float* Of = (float*)Pbuf;                   // row stride 33 dwords
#pragma unroll
    for (int mt = 0; mt < 4; ++mt)
#pragma unroll
        for (int rg = 0; rg < 4; ++rg) {
            int i = mt * 16 + q * 4 + rg;
            float sc = rinv[mt][rg];
            Of[i * 33 + r16]      = o[mt][0][rg] * sc;
            Of[i * 33 + 16 + r16] = o[mt][1][rg] * sc;
        }
    __syncthreads();   // fence: Of writes before cross-lane reads
    {
        int pix = wpix(wh, ww, lane);
        ushort* ob = (ushort*)attnout + (size_t)(b * HW + pix) * 128 + head * 32;
#pragma unroll
        for (int g = 0; g < 4; ++g) {
            short8 o8;
#pragma unroll
            for (int e = 0; e < 8; ++e) o8[e] = (short)(ushort)f2bf(Of[lane * 33 + g * 8 + e]);
            *(short8*)(ob + g * 8) = o8;
        }
    }
}

// ---------------------------------------------------------------- launch
extern "C" void kernel_launch(void* const* d_in, const int* in_sizes, int n_in,
                              void* d_out, int out_size, void* d_ws, size_t ws_size,
                              hipStream_t stream)
{
    const float* x     = (const float*)d_in[0];
    const float* cg_s  = (const float*)d_in[1];
    const float* cg_b  = (const float*)d_in[2];
    const float* pw1_w = (const float*)d_in[3];
    const float* pw1_b = (const float*)d_in[4];
    const float* dw_w  = (const float*)d_in[5];
    const float* dw_b  = (const float*)d_in[6];
    const float* pw2_w = (const float*)d_in[7];
    const float* pw2_b = (const float*)d_in[8];
    const float* beta  = (const float*)d_in[9];
    const float* at_s  = (const float*)d_in[10];
    const float* at_b  = (const float*)d_in[11];
    const float* qkv_w = (const float*)d_in[12];
    const float* qkv_b = (const float*)d_in[13];
    const float* rpe   = (const float*)d_in[14];
    const float* proj_w= (const float*)d_in[15];
    const float* proj_b= (const float*)d_in[16];
    const float* alpha = (const float*)d_in[17];
    const float* ff_s  = (const float*)d_in[18];
    const float* ff_b  = (const float*)d_in[19];
    const float* fc1_w = (const float*)d_in[20];
    const float* fc1_b = (const float*)d_in[21];
    const float* fc2_w = (const float*)d_in[22];
    const float* fc2_b = (const float*)d_in[23];
    const float* gamma = (const float*)d_in[24];
    float* out = (float*)d_out;

    char* ws = (char*)d_ws;
    __hip_bfloat16* Xn    = (__hip_bfloat16*)ws;
    __hip_bfloat16* t1    = (__hip_bfloat16*)(ws + 18874368);
    __hip_bfloat16* qkvb  = t1;
    __hip_bfloat16* tg    = (__hip_bfloat16*)(ws + 94371840);
    __hip_bfloat16* attno = tg;
    char* wsw = ws + 132120576;
    ushort* w1b  = (ushort*)(wsw);             // 512*128
    ushort* w2b  = (ushort*)(wsw + 131072);    // 128*256
    ushort* wqb  = (ushort*)(wsw + 196608);    // 384*128
    ushort* wpb  = (ushort*)(wsw + 294912);    // 128*128
    ushort* wf1b = (ushort*)(wsw + 327680);    // 512*128 (paired u/v)
    ushort* wf2b = (ushort*)(wsw + 458752);    // 128*256
    float*  dwt  = (float*) (wsw + 524288);    // 9*512 fp32
    float*  bg1  = (float*) (wsw + 542720);    // 512 fp32 (paired fc1 bias)

    wconv_kernel<<<1044, 256, 0, stream>>>(pw1_w, pw2_w, qkv_w, proj_w, fc1_w, fc2_w, dw_w, fc1_b,
                                           w1b, w2b, wqb, wpb, wf1b, wf2b, dwt, bg1);

    // ---- stage 1: conv_gated_block (pw2 fuses residual + at-RMSNorm)
    rmsnorm_t_kernel<<<288, 256, 0, stream>>>(x, cg_s, cg_b, Xn);
    gemm_kernel<128, 0><<<dim3(576, 4), 256, 0, stream>>>(Xn, (__hip_bfloat16*)w1b, pw1_b, 512, t1);
    dwgate_kernel<<<4608, 256, 0, stream>>>(t1, dwt, dw_b, tg);
    gemm_n128_kernel<256, true><<<1152, 256, 0, stream>>>(tg, (__hip_bfloat16*)w2b, pw2_b,
                                                          x, out, beta, at_s, at_b, Xn);

    // ---- stage 2: window attention (proj fuses residual + ff-RMSNorm)
    gemm_kernel<128, 0><<<dim3(576, 3), 256, 0, stream>>>(Xn, (__hip_bfloat16*)wqb, qkv_b, 384, qkvb);
    attn_kernel<<<dim3(576, 2), 256, 0, stream>>>(qkvb, rpe, attno);
    gemm_n128_kernel<128, true><<<1152, 256, 0, stream>>>(attno, (__hip_bfloat16*)wpb, proj_b,
                                                          out, out, alpha, ff_s, ff_b, Xn);

    // ---- stage 3: gated FFN (gate fused into fc1 GEMM epilogue)
    gemm_kernel<128, 2><<<dim3(576, 4), 256, 0, stream>>>(Xn, (__hip_bfloat16*)wf1b, bg1, 512, tg);
    gemm_n128_kernel<256, false><<<1152, 256, 0, stream>>>(tg, (__hip_bfloat16*)wf2b, fc2_b,
                                                           out, out, gamma, nullptr, nullptr, nullptr);
}

// Round 12
// 369.952 us; speedup vs baseline: 1.2511x; 1.0236x over previous
//
#include <hip/hip_runtime.h>
#include <hip/hip_bf16.h>
#include <math.h>

#define HW   36864        // 192*192
#define BHW  73728        // 2*HW

typedef float f32x4 __attribute__((ext_vector_type(4)));
typedef short short8 __attribute__((ext_vector_type(8)));
typedef short s16x4 __attribute__((ext_vector_type(4)));   // NB: 'short4' is a HIP built-in type

__device__ __forceinline__ unsigned f2bf(float f) {        // fp32 -> bf16 bits, RNE
    unsigned u = __float_as_uint(f);
    return (u + 0x7fffu + ((u >> 16) & 1u)) >> 16;
}
__device__ __forceinline__ float bf2f(unsigned short s) {  // bf16 bits -> fp32
    return __uint_as_float(((unsigned)s) << 16);
}
// tanh-approx gelu; <1e-3 abs dev from erf-gelu, ~7 instr vs ~25 for erff.
__device__ __forceinline__ float gelu_fast(float x) {
    float y = 1.5957691216057308f * fmaf(0.044715f * x * x, x, x);
    return x / (1.0f + __expf(-y));
}

// ---------------------------------------------------------------- weight prep
// fc1 weights/bias PAIRED: col 2c = u-channel c, col 2c+1 = v-channel c (fused gate epilogue).
__global__ __launch_bounds__(256)
void wconv_kernel(const float* __restrict__ w1, const float* __restrict__ w2,
                  const float* __restrict__ wq, const float* __restrict__ wp,
                  const float* __restrict__ wf1, const float* __restrict__ wf2,
                  const float* __restrict__ dww, const float* __restrict__ fb1,
                  ushort* __restrict__ o1, ushort* __restrict__ o2, ushort* __restrict__ oq,
                  ushort* __restrict__ op, ushort* __restrict__ of1, ushort* __restrict__ of2,
                  float* __restrict__ dwt, float* __restrict__ bg)
{
    int i = blockIdx.x * 256 + threadIdx.x;
    if      (i <  65536) o1 [i         ] = (ushort)f2bf(w1 [i         ]);
    else if (i <  98304) o2 [i -  65536] = (ushort)f2bf(w2 [i -  65536]);
    else if (i < 147456) oq [i -  98304] = (ushort)f2bf(wq [i -  98304]);
    else if (i < 163840) op [i - 147456] = (ushort)f2bf(wp [i - 147456]);
    else if (i < 229376) {
        int j = i - 163840;            // paired fc1: col=j>>7, k=j&127
        int col = j >> 7, k = j & 127;
        of1[j] = (ushort)f2bf(wf1[((size_t)((col & 1) * 256 + (col >> 1))) * 128 + k]);
    }
    else if (i < 262144) of2[i - 229376] = (ushort)f2bf(wf2[i - 229376]);
    else if (i < 266752) {
        int j = i - 262144;            // j = tap*512 + c
        int tap = j >> 9, c = j & 511;
        dwt[j] = dww[c * 9 + tap];
    }
    else if (i < 267264) {
        int j = i - 266752;            // paired fc1 bias
        bg[j] = fb1[(j & 1) * 256 + (j >> 1)];
    }
}

// ---------------------------------------------------------------- rmsnorm (NCHW fp32 -> pixel-major bf16)
__global__ __launch_bounds__(256)
void rmsnorm_t_kernel(const float* __restrict__ src, const float* __restrict__ s,
                      const float* __restrict__ bi, __hip_bfloat16* __restrict__ dst)
{
    int P = blockIdx.x * 256 + threadIdx.x;          // pixel id in [0, BHW)
    int b = P / HW, pp = P - b * HW;
    const float* xb = src + (size_t)b * 128 * HW + pp;
    float ss = 0.f;
#pragma unroll 8
    for (int c = 0; c < 128; ++c) { float v = xb[(size_t)c * HW]; ss = fmaf(v, v, ss); }
    float inv = 1.0f / sqrtf(ss * 0.0078125f + 1e-6f);
    unsigned* drow = (unsigned*)(dst + (size_t)P * 128);
#pragma unroll 4
    for (int c = 0; c < 128; c += 2) {
        float v0 = fmaf(s[c]     * xb[(size_t)c * HW],       inv, bi[c]);
        float v1 = fmaf(s[c + 1] * xb[(size_t)(c + 1) * HW], inv, bi[c + 1]);
        drow[c >> 1] = f2bf(v0) | (f2bf(v1) << 16);
    }
}

// ---------------------------------------------------------------- MFMA GEMM, 64x128 tile
// Grid (1152, N/128): 2x the blocks of the 128-tile version -> better latency overlap
// at K=128/256 where each block is mostly prologue+barriers (r11: occupancy 29%).
// MODE 0: store bf16 pixel-major (BHW,N). MODE 2: paired u/v cols -> u*gelu(v) (BHW,256).
template<int K, int MODE>
__global__ __launch_bounds__(256)
void gemm_kernel(const __hip_bfloat16* __restrict__ Abf, const __hip_bfloat16* __restrict__ Wbf,
                 const float* __restrict__ bias, int N,
                 __hip_bfloat16* __restrict__ outb)
{
    __shared__ char smem[12288];
    short* sA = (short*)smem;                 // 64 rows x 32k = 4KB
    short* sB = sA + 2048;                    // 128 rows x 32k = 8KB

    const short* A = (const short*)Abf;
    const short* W = (const short*)Wbf;

    int t = threadIdx.x;
    int lane = t & 63, wv = t >> 6;
    int m0 = blockIdx.x * 64;
    int n0 = blockIdx.y * 128;
    int q = lane >> 4, r16 = lane & 15;

    f32x4 acc[4][2];
#pragma unroll
    for (int nt = 0; nt < 2; ++nt) {
        float bv = bias[n0 + wv * 32 + nt * 16 + r16];
#pragma unroll
        for (int mt = 0; mt < 4; ++mt) acc[mt][nt] = (f32x4){bv, bv, bv, bv};
    }

    for (int kk = 0; kk < K; kk += 32) {
        {   // A: wave wv stages rows wv*16 .. +16
            int rbase = wv * 16;
            int row = rbase + (lane >> 2);
            int kc = (lane & 3) ^ ((row >> 1) & 3);
            const short* ga = A + (size_t)(m0 + row) * K + kk + kc * 8;
            __builtin_amdgcn_global_load_lds((const __attribute__((address_space(1))) void*)ga,
                                             (__attribute__((address_space(3))) void*)(sA + rbase * 32), 16, 0, 0);
        }
#pragma unroll
        for (int i = 0; i < 2; ++i) {   // B: wave wv stages weight rows wv*32 .. +32
            int rbase = wv * 32 + i * 16;
            int row = rbase + (lane >> 2);
            int kc = (lane & 3) ^ ((row >> 1) & 3);
            const short* gb = W + (size_t)(n0 + row) * K + kk + kc * 8;
            __builtin_amdgcn_global_load_lds((const __attribute__((address_space(1))) void*)gb,
                                             (__attribute__((address_space(3))) void*)(sB + rbase * 32), 16, 0, 0);
        }
        __syncthreads();

        short8 af[4], bf[2];
#pragma unroll
        for (int mt = 0; mt < 4; ++mt) {
            int r = mt * 16 + r16;
            af[mt] = *(const short8*)(sA + (r * 4 + (q ^ ((r >> 1) & 3))) * 8);
        }
#pragma unroll
        for (int nt = 0; nt < 2; ++nt) {
            int r = wv * 32 + nt * 16 + r16;
            bf[nt] = *(const short8*)(sB + (r * 4 + (q ^ ((r >> 1) & 3))) * 8);
        }
#pragma unroll
        for (int mt = 0; mt < 4; ++mt)
#pragma unroll
            for (int nt = 0; nt < 2; ++nt)
                acc[mt][nt] = __builtin_amdgcn_mfma_f32_16x16x32_bf16(af[mt], bf[nt], acc[mt][nt], 0, 0, 0);
        __syncthreads();
    }

    if constexpr (MODE == 0) {
        ushort* ob = (ushort*)outb;
#pragma unroll
        for (int mt = 0; mt < 4; ++mt) {
            int row0 = m0 + mt * 16 + q * 4;
#pragma unroll
            for (int nt = 0; nt < 2; ++nt) {
                int col = n0 + wv * 32 + nt * 16 + r16;
#pragma unroll
                for (int rg = 0; rg < 4; ++rg)
                    ob[(size_t)(row0 + rg) * N + col] = (ushort)f2bf(acc[mt][nt][rg]);
            }
        }
    } else {   // MODE 2
        ushort* ob = (ushort*)outb;
        int parity = r16 & 1;
#pragma unroll
        for (int mt = 0; mt < 4; ++mt) {
            int row0 = m0 + mt * 16 + q * 4;
#pragma unroll
            for (int nt = 0; nt < 2; ++nt) {
                int ch = (n0 + wv * 32 + nt * 16 + r16) >> 1;
#pragma unroll
                for (int rg = 0; rg < 4; ++rg) {
                    float val = acc[mt][nt][rg];
                    float part = __shfl_xor(val, 1);
                    float uu = parity ? part : val;
                    float vv = parity ? val : part;
                    float g = uu * gelu_fast(vv);
                    if (!parity)
                        ob[(size_t)(row0 + rg) * 256 + ch] = (ushort)f2bf(g);
                }
            }
        }
    }
}

// ---------------------------------------------------------------- MFMA GEMM, N=128, 64-row tile
template<int K, bool RMS>
__global__ __launch_bounds__(256)
void gemm_n128_kernel(const __hip_bfloat16* __restrict__ Abf, const __hip_bfloat16* __restrict__ Wbf,
                      const float* __restrict__ bias,
                      const float* __restrict__ rsrc, float* __restrict__ rdst,
                      const float* __restrict__ scale,
                      const float* __restrict__ rms_s, const float* __restrict__ rms_b,
                      __hip_bfloat16* __restrict__ xn)
{
    constexpr int SMEM = RMS ? 39424 : 34816;
    __shared__ char smem[SMEM];
    short* sA = (short*)smem;                 // 64 rows x 32k = 4KB
    short* sB = sA + 2048;                    // 128 rows x 32k = 8KB
    float* sEp = (float*)smem;                // [128 ch][68 px] = 34816 (overlays staging)
    float* sPar = (float*)(smem + 34816);     // RMS: [64 px][17]
    float* sInv = (float*)(smem + 39168);     // RMS: [64 px]

    const short* A = (const short*)Abf;
    const short* W = (const short*)Wbf;

    int t = threadIdx.x;
    int lane = t & 63, wv = t >> 6;
    int m0 = blockIdx.x * 64;
    int q = lane >> 4, r16 = lane & 15;

    f32x4 acc[4][2];
#pragma unroll
    for (int nt = 0; nt < 2; ++nt) {
        float bv = bias[wv * 32 + nt * 16 + r16];
#pragma unroll
        for (int mt = 0; mt < 4; ++mt) acc[mt][nt] = (f32x4){bv, bv, bv, bv};
    }

    for (int kk = 0; kk < K; kk += 32) {
        {   // A: wave wv stages rows wv*16 .. +16
            int rbase = wv * 16;
            int row = rbase + (lane >> 2);
            int kc = (lane & 3) ^ ((row >> 1) & 3);
            const short* ga = A + (size_t)(m0 + row) * K + kk + kc * 8;
            __builtin_amdgcn_global_load_lds((const __attribute__((address_space(1))) void*)ga,
                                             (__attribute__((address_space(3))) void*)(sA + rbase * 32), 16, 0, 0);
        }
#pragma unroll
        for (int i = 0; i < 2; ++i) {   // B: wave wv stages channel rows wv*32 .. +32
            int rbase = wv * 32 + i * 16;
            int row = rbase + (lane >> 2);
            int kc = (lane & 3) ^ ((row >> 1) & 3);
            const short* gb = W + (size_t)row * K + kk + kc * 8;
            __builtin_amdgcn_global_load_lds((const __attribute__((address_space(1))) void*)gb,
                                             (__attribute__((address_space(3))) void*)(sB + rbase * 32), 16, 0, 0);
        }
        __syncthreads();

        short8 af[4], bf[2];
#pragma unroll
        for (int mt = 0; mt < 4; ++mt) {
            int r = mt * 16 + r16;
            af[mt] = *(const short8*)(sA + (r * 4 + (q ^ ((r >> 1) & 3))) * 8);
        }
#pragma unroll
        for (int nt = 0; nt < 2; ++nt) {
            int r = wv * 32 + nt * 16 + r16;
            bf[nt] = *(const short8*)(sB + (r * 4 + (q ^ ((r >> 1) & 3))) * 8);
        }
#pragma unroll
        for (int mt = 0; mt < 4; ++mt)
#pragma unroll
            for (int nt = 0; nt < 2; ++nt)
                acc[mt][nt] = __builtin_amdgcn_mfma_f32_16x16x32_bf16(af[mt], bf[nt], acc[mt][nt], 0, 0, 0);
        __syncthreads();
    }

    // single-pass epilogue: all 4 waves write their C fragments
#pragma unroll
    for (int mt = 0; mt < 4; ++mt)
#pragma unroll
        for (int nt = 0; nt < 2; ++nt) {
            int c = wv * 32 + nt * 16 + r16;
            int px = mt * 16 + q * 4;
#pragma unroll
            for (int rg = 0; rg < 4; ++rg)
                sEp[c * 68 + px + rg] = acc[mt][nt][rg];
        }
    __syncthreads();

    int c16 = t >> 4, l16 = t & 15;
    int p0 = m0 + l16 * 4;
    int b = p0 / HW, pp = p0 - b * HW;
    float sc = scale[0];
    f32x4 ov[8];
    f32x4 ps = (f32x4){0.f, 0.f, 0.f, 0.f};
#pragma unroll
    for (int i = 0; i < 8; ++i) {
        int c = c16 + i * 16;
        f32x4 v = *(const f32x4*)&sEp[c * 68 + l16 * 4];
        size_t gi = (size_t)(b * 128 + c) * HW + pp;
        f32x4 r = *(const f32x4*)&rsrc[gi];
        f32x4 o = r + sc * v;
        *(f32x4*)&rdst[gi] = o;
        if constexpr (RMS) {
            ov[i] = o;
#pragma unroll
            for (int rg = 0; rg < 4; ++rg) ps[rg] = fmaf(o[rg], o[rg], ps[rg]);
        }
    }
    if constexpr (RMS) {
#pragma unroll
        for (int rg = 0; rg < 4; ++rg) sPar[(l16 * 4 + rg) * 17 + c16] = ps[rg];
        __syncthreads();               // also fences sEp reads before sXn overlay
        if (t < 64) {
            float ssum = 0.f;
#pragma unroll
            for (int j = 0; j < 16; ++j) ssum += sPar[t * 17 + j];
            sInv[t] = 1.0f / sqrtf(ssum * 0.0078125f + 1e-6f);
        }
        __syncthreads();
        float iv[4];
#pragma unroll
        for (int rg = 0; rg < 4; ++rg) iv[rg] = sInv[l16 * 4 + rg];
        ushort* sXn = (ushort*)smem;   // overlay dead sEp: [64 px][132 ch-pad]
#pragma unroll
        for (int i = 0; i < 8; ++i) {
            int c = c16 + i * 16;
            float scs = rms_s[c], bcs = rms_b[c];
#pragma unroll
            for (int rg = 0; rg < 4; ++rg)
                sXn[(l16 * 4 + rg) * 132 + c] = (ushort)f2bf(fmaf(scs * ov[i][rg], iv[rg], bcs));
        }
        __syncthreads();
        {
            int px = t >> 2, qd = t & 3;
            const ushort* src = sXn + px * 132 + qd * 32;
            ushort* dst = (ushort*)xn + (size_t)(m0 + px) * 128 + qd * 32;
#pragma unroll
            for (int g = 0; g < 4; ++g)
                *(short8*)(dst + g * 8) = *(const short8*)(src + g * 8);
        }
    }
}

// ---------------------------------------------------------------- dwconv3x3 + gate, full-row v5
// 4x4 pixel tile; tc=t&63 spans ALL 256 gate channels (4 ch/thread), tp=t>>6 = pixel column.
// Every wave-level load/store is a full contiguous 512B pixel row (no partial-sector
// write amplification). Weights hoisted once; bounds via clamp+mask; fast gelu.
__global__ __launch_bounds__(256, 3)
void dwgate_kernel(const __hip_bfloat16* __restrict__ t1, const float* __restrict__ dwt,
                   const float* __restrict__ dwb, __hip_bfloat16* __restrict__ tg)
{
    int t = threadIdx.x;
    int tc = t & 63;                   // channel chunk (4 ch) over all 256
    int tp = t >> 6;                   // 0..3 pixel column
    int bx = blockIdx.x;               // 4608 = 2 * 48 * 48
    int b = bx / 2304; int tt = bx % 2304;
    int th = tt / 48, tw = tt % 48;
    int h0 = th * 4, w = tw * 4 + tp;
    int cu = tc * 4;                   // u-channel base 0..252
    const ushort* t1u = (const ushort*)t1;

    f32x4 wu[9], wv[9];
#pragma unroll
    for (int tap = 0; tap < 9; ++tap) {
        wu[tap] = *(const f32x4*)(dwt + tap * 512 + cu);
        wv[tap] = *(const f32x4*)(dwt + tap * 512 + 256 + cu);
    }
    f32x4 bu = *(const f32x4*)(dwb + cu);
    f32x4 bv = *(const f32x4*)(dwb + 256 + cu);

    f32x4 au[4], av[4];
#pragma unroll
    for (int py = 0; py < 4; ++py) { au[py] = bu; av[py] = bv; }

#pragma unroll
    for (int r = 0; r < 6; ++r) {                    // source row h0-1+r
        int hh = h0 - 1 + r;
        bool okr = (unsigned)hh < 192u;
        int hhc = okr ? hh : 0;
#pragma unroll
        for (int dxi = 0; dxi < 3; ++dxi) {
            int w2 = w + dxi - 1;
            bool ok = okr && ((unsigned)w2 < 192u);
            int w2c = (w2 < 0) ? 0 : ((w2 > 191) ? 191 : w2);
            const ushort* p = t1u + (size_t)(b * HW + hhc * 192 + w2c) * 512 + cu;
            s16x4 u4 = *(const s16x4*)p;
            s16x4 v4 = *(const s16x4*)(p + 256);
            f32x4 uf, vf;
#pragma unroll
            for (int e = 0; e < 4; ++e) {
                uf[e] = ok ? bf2f((ushort)u4[e]) : 0.f;
                vf[e] = ok ? bf2f((ushort)v4[e]) : 0.f;
            }
#pragma unroll
            for (int py = 0; py < 4; ++py) {
                int dy = r - 1 - py;
                if (dy < -1 || dy > 1) continue;     // compile-time after unroll
                int tap = (dy + 1) * 3 + dxi;
#pragma unroll
                for (int e = 0; e < 4; ++e) {
                    au[py][e] = fmaf(wu[tap][e], uf[e], au[py][e]);
                    av[py][e] = fmaf(wv[tap][e], vf[e], av[py][e]);
                }
            }
        }
    }
#pragma unroll
    for (int py = 0; py < 4; ++py) {
        s16x4 o4;
#pragma unroll
        for (int e = 0; e < 4; ++e) o4[e] = (short)(ushort)f2bf(au[py][e] * gelu_fast(av[py][e]));
        int gp = b * HW + (h0 + py) * 192 + w;
        *(s16x4*)((ushort*)tg + (size_t)gp * 256 + cu) = o4;
    }
}

// ---------------------------------------------------------------- windowed attention (MFMA)
__device__ __forceinline__ int wpix(int wh, int ww, int m) {
    int ty = m >> 3, tx = m & 7;
    int hs = wh * 8 + ty + 4; if (hs >= 192) hs -= 192;
    int wsc = ww * 8 + tx + 4; if (wsc >= 192) wsc -= 192;
    return hs * 192 + wsc;
}
__device__ __forceinline__ int wreg(int wh, int ww, int m) {   // shift-mask region id
    int hr = wh * 8 + (m >> 3), wr = ww * 8 + (m & 7);
    return ((hr < 184) ? 0 : (hr < 188) ? 1 : 2) * 3 +
           ((wr < 184) ? 0 : (wr < 188) ? 1 : 2);
}

__global__ __launch_bounds__(256)
void attn_kernel(const __hip_bfloat16* __restrict__ qkv, const float* __restrict__ rpe,
                 __hip_bfloat16* __restrict__ attnout)
{
    __shared__ char smem[54288];
    int t = threadIdx.x;
    int lane = t & 63, head = t >> 6;
    int wh = blockIdx.x / 24, ww = blockIdx.x % 24;
    int b = blockIdx.y;
    int q = lane >> 4, r16 = lane & 15;

    float* rpe_s = (float*)(smem + 50688);
    for (int i = t; i < 900; i += 256) rpe_s[i] = rpe[i];

    char* Pbuf  = smem + head * 12672;
    char* VTbuf = Pbuf + 8448;
    const ushort* qkvu = (const ushort*)qkv;

    short8 aq[4], bk[4];
#pragma unroll
    for (int mt = 0; mt < 4; ++mt) {
        int pix = wpix(wh, ww, mt * 16 + r16);
        const ushort* rowp = qkvu + (size_t)(b * HW + pix) * 384 + head * 32 + q * 8;
        aq[mt] = *(const short8*)rowp;
        bk[mt] = *(const short8*)(rowp + 128);
    }
    {
        int pix = wpix(wh, ww, lane);
        const ushort* vp = qkvu + (size_t)(b * HW + pix) * 384 + 256 + head * 32;
        ushort* vt = (ushort*)VTbuf;           // VT[d][j]: row stride 66 ushorts
#pragma unroll
        for (int g = 0; g < 4; ++g) {
            short8 v8 = *(const short8*)(vp + g * 8);
#pragma unroll
            for (int e = 0; e < 8; ++e) vt[(g * 8 + e) * 66 + lane] = (ushort)v8[e];
        }
    }
    __syncthreads();

    f32x4 s[4][4];
#pragma unroll
    for (int mt = 0; mt < 4; ++mt)
#pragma unroll
        for (int nt = 0; nt < 4; ++nt) s[mt][nt] = (f32x4){0.f, 0.f, 0.f, 0.f};
#pragma unroll
    for (int mt = 0; mt < 4; ++mt)
#pragma unroll
        for (int nt = 0; nt < 4; ++nt)
            s[mt][nt] = __builtin_amdgcn_mfma_f32_16x16x32_bf16(aq[mt], bk[nt], s[mt][nt], 0, 0, 0);

    bool edge = (wh == 23) || (ww == 23);
    int tyj[4], txj[4], rgj[4];
#pragma unroll
    for (int nt = 0; nt < 4; ++nt) {
        int j = nt * 16 + r16;
        tyj[nt] = j >> 3; txj[nt] = j & 7;
        rgj[nt] = wreg(wh, ww, j);
    }
    float rinv[4][4];
#pragma unroll
    for (int mt = 0; mt < 4; ++mt) {
#pragma unroll
        for (int rg = 0; rg < 4; ++rg) {
            int i = mt * 16 + q * 4 + rg;
            int tyi = i >> 3, txi = i & 7;
            int rgi = edge ? wreg(wh, ww, i) : 0;
            float mx = -INFINITY;
#pragma unroll
            for (int nt = 0; nt < 4; ++nt) {
                float v = s[mt][nt][rg] * 0.17677669529663689f
                        + rpe_s[((tyi - tyj[nt] + 7) * 15 + (txi - txj[nt] + 7)) * 4 + head];
                if (edge && rgi != rgj[nt]) v = -INFINITY;
                s[mt][nt][rg] = v;
                mx = fmaxf(mx, v);
            }
            mx = fmaxf(mx, __shfl_xor(mx, 1));
            mx = fmaxf(mx, __shfl_xor(mx, 2));
            mx = fmaxf(mx, __shfl_xor(mx, 4));
            mx = fmaxf(mx, __shfl_xor(mx, 8));
            float sum = 0.f;
#pragma unroll
            for (int nt = 0; nt < 4; ++nt) {
                float e = __expf(s[mt][nt][rg] - mx);
                s[mt][nt][rg] = e;
                sum += e;
            }
            sum += __shfl_xor(sum, 1);
            sum += __shfl_xor(sum, 2);
            sum += __shfl_xor(sum, 4);
            sum += __shfl_xor(sum, 8);
            rinv[mt][rg] = 1.0f / sum;
        }
    }

    ushort* Pu = (ushort*)Pbuf;                 // row stride 66 ushorts
#pragma unroll
    for (int mt = 0; mt < 4; ++mt)
#pragma unroll
        for (int rg = 0; rg < 4; ++rg) {
            int i = mt * 16 + q * 4 + rg;
#pragma unroll
            for (int nt = 0; nt < 4; ++nt)
                Pu[i * 66 + nt * 16 + r16] = (ushort)f2bf(s[mt][nt][rg]);
        }
    __syncthreads();   // fence: P ushort-writes before uint-reads (TBAA)

    f32x4 o[4][2];
#pragma unroll
    for (int mt = 0; mt < 4; ++mt) { o[mt][0] = (f32x4){0,0,0,0}; o[mt][1] = (f32x4){0,0,0,0}; }
    const uint* Pw = (const uint*)Pbuf;         // dword units, row stride 33
    const uint* Vw = (const uint*)VTbuf;
#pragma unroll
    for (int ks = 0; ks < 2; ++ks) {
        short8 ap[4];
#pragma unroll
        for (int mt = 0; mt < 4; ++mt) {
            int base = (mt * 16 + r16) * 33 + ks * 16 + q * 4;
            uint d0 = Pw[base], d1 = Pw[base + 1], d2 = Pw[base + 2], d3 = Pw[base + 3];
            union { uint u[4]; short8 s8; } cv; cv.u[0] = d0; cv.u[1] = d1; cv.u[2] = d2; cv.u[3] = d3;
            ap[mt] = cv.s8;
        }
        short8 bv[2];
#pragma unroll
        for (int nt = 0; nt < 2; ++nt) {
            int base = (nt * 16 + r16) * 33 + ks * 16 + q * 4;
            uint d0 = Vw[base], d1 = Vw[base + 1], d2 = Vw[base + 2], d3 = Vw[base + 3];
            union { uint u[4]; short8 s8; } cv; cv.u[0] = d0; cv.u[1] = d1; cv.u[2] = d2; cv.u[3] = d3;
            bv[nt] = cv.s8;
        }
#pragma unroll
        for (int mt = 0; mt < 4; ++mt)
#pragma unroll
            for (int nt = 0; nt < 2; ++nt)
                o[mt][nt] = __builtin_amdgcn_mfma_f32_16x16x32_bf16(ap[mt], bv[nt], o[mt][nt], 0, 0, 0);
    }
    __syncthreads();   // fence: P uint-reads complete before Of float-overwrite (TBAA WAR)

    float* Of = (float*)Pbuf;                   // row stride 33 dwords
#pragma unroll
    for (int mt = 0; mt < 4; ++mt)
#pragma unroll
        for (int rg = 0; rg < 4; ++rg) {
            int i = mt * 16 + q * 4 + rg;
            float sc = rinv[mt][rg];
            Of[i * 33 + r16]      = o[mt][0][rg] * sc;
            Of[i * 33 + 16 + r16] = o[mt][1][rg] * sc;
        }
    __syncthreads();   // fence: Of writes before cross-lane reads
    {
        int pix = wpix(wh, ww, lane);
        ushort* ob = (ushort*)attnout + (size_t)(b * HW + pix) * 128 + head * 32;
#pragma unroll
        for (int g = 0; g < 4; ++g) {
            short8 o8;
#pragma unroll
            for (int e = 0; e < 8; ++e) o8[e] = (short)(ushort)f2bf(Of[lane * 33 + g * 8 + e]);
            *(short8*)(ob + g * 8) = o8;
        }
    }
}

// ---------------------------------------------------------------- launch
extern "C" void kernel_launch(void* const* d_in, const int* in_sizes, int n_in,
                              void* d_out, int out_size, void* d_ws, size_t ws_size,
                              hipStream_t stream)
{
    const float* x     = (const float*)d_in[0];
    const float* cg_s  = (const float*)d_in[1];
    const float* cg_b  = (const float*)d_in[2];
    const float* pw1_w = (const float*)d_in[3];
    const float* pw1_b = (const float*)d_in[4];
    const float* dw_w  = (const float*)d_in[5];
    const float* dw_b  = (const float*)d_in[6];
    const float* pw2_w = (const float*)d_in[7];
    const float* pw2_b = (const float*)d_in[8];
    const float* beta  = (const float*)d_in[9];
    const float* at_s  = (const float*)d_in[10];
    const float* at_b  = (const float*)d_in[11];
    const float* qkv_w = (const float*)d_in[12];
    const float* qkv_b = (const float*)d_in[13];
    const float* rpe   = (const float*)d_in[14];
    const float* proj_w= (const float*)d_in[15];
    const float* proj_b= (const float*)d_in[16];
    const float* alpha = (const float*)d_in[17];
    const float* ff_s  = (const float*)d_in[18];
    const float* ff_b  = (const float*)d_in[19];
    const float* fc1_w = (const float*)d_in[20];
    const float* fc1_b = (const float*)d_in[21];
    const float* fc2_w = (const float*)d_in[22];
    const float* fc2_b = (const float*)d_in[23];
    const float* gamma = (const float*)d_in[24];
    float* out = (float*)d_out;

    char* ws = (char*)d_ws;
    __hip_bfloat16* Xn    = (__hip_bfloat16*)ws;
    __hip_bfloat16* t1    = (__hip_bfloat16*)(ws + 18874368);
    __hip_bfloat16* qkvb  = t1;
    __hip_bfloat16* tg    = (__hip_bfloat16*)(ws + 94371840);
    __hip_bfloat16* attno = tg;
    char* wsw = ws + 132120576;
    ushort* w1b  = (ushort*)(wsw);             // 512*128
    ushort* w2b  = (ushort*)(wsw + 131072);    // 128*256
    ushort* wqb  = (ushort*)(wsw + 196608);    // 384*128
    ushort* wpb  = (ushort*)(wsw + 294912);    // 128*128
    ushort* wf1b = (ushort*)(wsw + 327680);    // 512*128 (paired u/v)
    ushort* wf2b = (ushort*)(wsw + 458752);    // 128*256
    float*  dwt  = (float*) (wsw + 524288);    // 9*512 fp32
    float*  bg1  = (float*) (wsw + 542720);    // 512 fp32 (paired fc1 bias)

    wconv_kernel<<<1044, 256, 0, stream>>>(pw1_w, pw2_w, qkv_w, proj_w, fc1_w, fc2_w, dw_w, fc1_b,
                                           w1b, w2b, wqb, wpb, wf1b, wf2b, dwt, bg1);

    // ---- stage 1: conv_gated_block (pw2 fuses residual + at-RMSNorm)
    rmsnorm_t_kernel<<<288, 256, 0, stream>>>(x, cg_s, cg_b, Xn);
    gemm_kernel<128, 0><<<dim3(1152, 4), 256, 0, stream>>>(Xn, (__hip_bfloat16*)w1b, pw1_b, 512, t1);
    dwgate_kernel<<<4608, 256, 0, stream>>>(t1, dwt, dw_b, tg);
    gemm_n128_kernel<256, true><<<1152, 256, 0, stream>>>(tg, (__hip_bfloat16*)w2b, pw2_b,
                                                          x, out, beta, at_s, at_b, Xn);

    // ---- stage 2: window attention (proj fuses residual + ff-RMSNorm)
    gemm_kernel<128, 0><<<dim3(1152, 3), 256, 0, stream>>>(Xn, (__hip_bfloat16*)wqb, qkv_b, 384, qkvb);
    attn_kernel<<<dim3(576, 2), 256, 0, stream>>>(qkvb, rpe, attno);
    gemm_n128_kernel<128, true><<<1152, 256, 0, stream>>>(attno, (__hip_bfloat16*)wpb, proj_b,
                                                          out, out, alpha, ff_s, ff_b, Xn);

    // ---- stage 3: gated FFN (gate fused into fc1 GEMM epilogue)
    gemm_kernel<128, 2><<<dim3(1152, 4), 256, 0, stream>>>(Xn, (__hip_bfloat16*)wf1b, bg1, 512, tg);
    gemm_n128_kernel<256, false><<<1152, 256, 0, stream>>>(tg, (__hip_bfloat16*)wf2b, fc2_b,
                                                           out, out, gamma, nullptr, nullptr, nullptr);
}